// Round 16
// baseline (264.015 us; speedup 1.0000x reference)
//
#include <hip/hip_runtime.h>

#define BB 4
#define CC 96
#define NN 3136
#define FLTMAX 3.402823466e+38f
#define CAP 44
#define DELTA 1.0f
#define PREF_MARGIN 0.8f

typedef unsigned short ushort_t;
typedef __attribute__((ext_vector_type(8))) short bf16x8;
typedef __attribute__((ext_vector_type(4))) float f32x4;

// fp32 -> bf16 round-to-nearest-even
__device__ __forceinline__ ushort_t f2bf(float f) {
    unsigned u = __float_as_uint(f);
    unsigned r = (u + 0x7fff + ((u >> 16) & 1)) >> 16;
    return (ushort_t)r;
}
__device__ __forceinline__ float bf2f(ushort_t us) {
    return __uint_as_float(((unsigned)us) << 16);
}

// htile layout (per batch):
//   idx(n,c) = (((n>>5)*12 + (c>>3))*32 + (n&31))*8 + (c&7)

// ---------------- K1: fc1 -> h (b,c,n) + x2 + bf16 htile (hi only) + hT ------
__global__ __launch_bounds__(256) void k_fc1(const float* __restrict__ x, const float* __restrict__ w,
                                             const float* __restrict__ bias, float* __restrict__ h,
                                             float* __restrict__ x2g,
                                             ushort_t* __restrict__ hAhi,
                                             float* __restrict__ hT) {
    __shared__ float sm[96 * 98 + 96 * 64];
    float* wT = sm;              // [c][o] pad 98
    float* xl = sm + 96 * 98;    // [c][64]
    const int tid = threadIdx.x;
    const int n0 = blockIdx.x * 64;
    const int b = blockIdx.y;
    for (int i = tid; i < 96 * 96; i += 256) {
        int o = i / 96, c = i - o * 96;
        wT[c * 98 + o] = w[i];
    }
    const float* xb = x + (size_t)b * CC * NN;
    for (int i = tid; i < 96 * 64; i += 256) {
        int c = i >> 6, nl = i & 63;
        xl[i] = xb[(size_t)c * NN + n0 + nl];
    }
    __syncthreads();
    const int tr = tid >> 4, tc = tid & 15;
    float acc[6][4];
#pragma unroll
    for (int i = 0; i < 6; ++i)
#pragma unroll
        for (int j = 0; j < 4; ++j) acc[i][j] = 0.f;
#pragma unroll 4
    for (int c = 0; c < 96; ++c) {
        float4 xv = *(const float4*)&xl[c * 64 + tc * 4];
        const float* wp = &wT[c * 98 + tr * 6];
        float2 w01 = *(const float2*)(wp);
        float2 w23 = *(const float2*)(wp + 2);
        float2 w45 = *(const float2*)(wp + 4);
        float wv[6] = {w01.x, w01.y, w23.x, w23.y, w45.x, w45.y};
        float xj[4] = {xv.x, xv.y, xv.z, xv.w};
#pragma unroll
        for (int i = 0; i < 6; ++i)
#pragma unroll
            for (int j = 0; j < 4; ++j) acc[i][j] = fmaf(wv[i], xj[j], acc[i][j]);
    }
    float* hb = h + (size_t)b * CC * NN;
    float* hTb = hT + (size_t)b * NN * 96;
    ushort_t* thi = hAhi + (size_t)b * 602112;
#pragma unroll
    for (int i = 0; i < 6; ++i) {
        float bi = bias[tr * 6 + i];
        acc[i][0] += bi; acc[i][1] += bi; acc[i][2] += bi; acc[i][3] += bi;
        float4 o4 = make_float4(acc[i][0], acc[i][1], acc[i][2], acc[i][3]);
        *(float4*)&hb[(size_t)(tr * 6 + i) * NN + n0 + tc * 4] = o4;
        const int c = tr * 6 + i;
        const int cpart = c >> 3;   // 12 parts of 8 channels
#pragma unroll
        for (int j = 0; j < 4; ++j) {
            const int n = n0 + tc * 4 + j;
            const int idx = (((n >> 5) * 12 + cpart) * 32 + (n & 31)) * 8 + (c & 7);
            thi[idx] = f2bf(acc[i][j]);
            hTb[(size_t)n * 96 + c] = acc[i][j];
        }
    }
    __syncthreads();   // wT/xl reads done -> reuse sm[0..1024) for x2 partials
#pragma unroll
    for (int j = 0; j < 4; ++j) {
        float s = 0.f;
#pragma unroll
        for (int i = 0; i < 6; ++i) s = fmaf(acc[i][j], acc[i][j], s);
        sm[tr * 64 + tc * 4 + j] = s;
    }
    __syncthreads();
    if (tid < 64) {
        float s = 0.f;
#pragma unroll
        for (int t = 0; t < 16; ++t) s += sm[t * 64 + tid];
        x2g[(size_t)b * NN + n0 + tid] = s;
    }
}

// hi-only MFMA tile body: 12 loads, 12 MFMA
#define MFMA_TILE_HI(t, acc0, acc1, acc2, acc3)                                       \
    {                                                                                 \
        const int abase_ = (t) * 6144;                                                \
        _Pragma("unroll")                                                             \
        for (int ks_ = 0; ks_ < 3; ++ks_) {                                           \
            const int base_ = abase_ + ks_ * 1024;                                    \
            bf16x8 a0_ = *(const bf16x8*)(hHi + base_ + aoff0);                       \
            bf16x8 a1_ = *(const bf16x8*)(hHi + base_ + aoff1);                       \
            bf16x8 a2_ = *(const bf16x8*)(hHi + base_ + 3072 + aoff0);                \
            bf16x8 a3_ = *(const bf16x8*)(hHi + base_ + 3072 + aoff1);                \
            acc0 = __builtin_amdgcn_mfma_f32_16x16x32_bf16(a0_, bhi[ks_], acc0, 0, 0, 0); \
            acc1 = __builtin_amdgcn_mfma_f32_16x16x32_bf16(a1_, bhi[ks_], acc1, 0, 0, 0); \
            acc2 = __builtin_amdgcn_mfma_f32_16x16x32_bf16(a2_, bhi[ks_], acc2, 0, 0, 0); \
            acc3 = __builtin_amdgcn_mfma_f32_16x16x32_bf16(a3_, bhi[ks_], acc3, 0, 0, 0); \
        }                                                                             \
    }

// ---------------- K3: threshold KNN filter, hi-only + reg score cache --------
// grid (98 n-blocks of 32, 4 m-quarters, B), 256 thr = 4 waves.
// Phase A: hi.hi approx scores; per-lane branchless top-3 (fp32); scores cached
//          in registers as packed bf16.
// thr[row] = exact 9th-smallest of staged 24 fp32 values + DELTA.
// Phase B: unpack cached scores, emit (bf16score<<16|m) for all <= thr.
__global__ __launch_bounds__(256) void k_dist(const ushort_t* __restrict__ hAhi,
                                              const float* __restrict__ x2,
                                              int* __restrict__ cand_cnt,
                                              int* __restrict__ cand_idx) {
    __shared__ float thrb[32][24];
    __shared__ float thr_s[32];
    __shared__ int   cnt[32];
    __shared__ int   list[32][CAP];
    const int tid = threadIdx.x;
    const int nb = blockIdx.x, q = blockIdx.y, b = blockIdx.z;
    const int w = tid >> 6, l = tid & 63;
    const int ln = l & 15, lq = l >> 4;
    const int p = w >> 1;
    const int kl_off = lq * 256;
    const ushort_t* hHi = hAhi + (size_t)b * 602112;
    const float* x2b = x2 + (size_t)b * NN;

    const int lane32n = (w & 1) * 16 + ln;
    bf16x8 bhi[3];
#pragma unroll
    for (int ks = 0; ks < 3; ++ks) {
        const int off = nb * 3072 + ks * 1024 + kl_off + lane32n * 8;
        bhi[ks] = *(const bf16x8*)(hHi + off);
    }
    const int aoff0 = kl_off + ln * 8;
    const int aoff1 = kl_off + (16 + ln) * 8;

    // quarter boundaries over 49 tiles: {0,13,25,37,49}
    const int qb0 = (q == 0) ? 0 : (q == 1) ? 13 : (q == 2) ? 25 : 37;
    const int qb1 = (q == 0) ? 13 : (q == 1) ? 25 : (q == 2) ? 37 : 49;
    const int tstart = qb0 + p;

    unsigned scache[7][8];   // packed bf16 scores: [tile][msub*2 + pair]
    // ---- Phase A ----
    float lv0 = FLTMAX, lv1 = FLTMAX, lv2 = FLTMAX;
#pragma unroll
    for (int ti = 0; ti < 7; ++ti) {
        const int t = tstart + 2 * ti;
        if (t < qb1) {
            const int m0 = t * 64;
            f32x4 acc0 = {0.f, 0.f, 0.f, 0.f}, acc1 = {0.f, 0.f, 0.f, 0.f};
            f32x4 acc2 = {0.f, 0.f, 0.f, 0.f}, acc3 = {0.f, 0.f, 0.f, 0.f};
            MFMA_TILE_HI(t, acc0, acc1, acc2, acc3);
#pragma unroll
            for (int msub = 0; msub < 4; ++msub) {
                f32x4 a = (msub == 0) ? acc0 : (msub == 1) ? acc1 : (msub == 2) ? acc2 : acc3;
                const int mb = m0 + msub * 16 + lq * 4;
                float4 xv = *(const float4*)&x2b[mb];
                float s0 = fmaf(-2.f, a[0], xv.x);
                float s1 = fmaf(-2.f, a[1], xv.y);
                float s2 = fmaf(-2.f, a[2], xv.z);
                float s3 = fmaf(-2.f, a[3], xv.w);
                scache[ti][msub * 2 + 0] = ((unsigned)f2bf(s0) << 16) | (unsigned)f2bf(s1);
                scache[ti][msub * 2 + 1] = ((unsigned)f2bf(s2) << 16) | (unsigned)f2bf(s3);
                float ss[4] = {s0, s1, s2, s3};
#pragma unroll
                for (int r = 0; r < 4; ++r) {
                    float v = ss[r];
                    float t0 = fminf(lv0, v);
                    lv0 = fmaxf(t0, lv1);
                    float t1 = fminf(t0, lv1);
                    lv1 = fmaxf(t1, lv2);
                    lv2 = fminf(t1, lv2);
                }
            }
        }
    }
    {
        const int sidx = (p * 4 + lq) * 3;
        thrb[lane32n][sidx + 0] = lv0;
        thrb[lane32n][sidx + 1] = lv1;
        thrb[lane32n][sidx + 2] = lv2;
    }
    __syncthreads();
    if (tid < 32) {
        float tmp[24];
#pragma unroll
        for (int j = 0; j < 24; ++j) tmp[j] = thrb[tid][j];
        float last = FLTMAX;
        for (int kk = 0; kk < 9; ++kk) {
            float mn = FLTMAX; int ms = 0;
            for (int j = 0; j < 24; ++j)
                if (tmp[j] < mn) { mn = tmp[j]; ms = j; }
            tmp[ms] = FLTMAX;
            last = mn;
        }
        thr_s[tid] = last + DELTA;
        cnt[tid] = 0;
    }
    __syncthreads();
    const float thr = thr_s[lane32n];

    // ---- Phase B: scan cached scores, emit all <= thr (no loads/MFMA) ----
#pragma unroll
    for (int ti = 0; ti < 7; ++ti) {
        const int t = tstart + 2 * ti;
        if (t < qb1) {
            const int m0 = t * 64;
#pragma unroll
            for (int msub = 0; msub < 4; ++msub) {
                const int mb = m0 + msub * 16 + lq * 4;
                const unsigned u01 = scache[ti][msub * 2 + 0];
                const unsigned u23 = scache[ti][msub * 2 + 1];
                unsigned bits[4] = {u01 >> 16, u01 & 0xffffu, u23 >> 16, u23 & 0xffffu};
#pragma unroll
                for (int r = 0; r < 4; ++r) {
                    if (bf2f((ushort_t)bits[r]) <= thr) {
                        int pos = atomicAdd(&cnt[lane32n], 1);
                        if (pos < CAP) list[lane32n][pos] = (int)((bits[r] << 16) | (unsigned)(mb + r));
                    }
                }
            }
        }
    }
    __syncthreads();
    // writeout
    const size_t rowbase = (size_t)b * NN + nb * 32;
    if (tid < 32) cand_cnt[(rowbase + tid) * 4 + q] = min(cnt[tid], CAP);
    for (int i = tid; i < 32 * CAP; i += 256) {
        int r = i / CAP, j = i - r * CAP;
        if (j < min(cnt[r], CAP))
            cand_idx[((rowbase + r) * 4 + q) * CAP + j] = list[r][j];
    }
}

// ---------------- K4: rank-by-counting exact rescore -> idx9 -----------------
// grid 3136 blocks x 256 thr = 4 waves; one wave per row n.
// No shfl reduces: stage values in LDS, each lane counts lex-smaller entries
// via uniform-address broadcast reads (pipelined, conflict-free).
// a9 = approx value of approx-rank-8 (multiset order stat -> deterministic);
// cutoff = a9 + PREF_MARGIN; exact rescore of passing candidates (superset of
// exact top-9); exact rank by (v, cj) -> direct ordered write of idx9.
__global__ __launch_bounds__(256) void k_merge9(const int* __restrict__ cand_cnt,
                                                const int* __restrict__ cand_idx,
                                                const float* __restrict__ hT,
                                                const float* __restrict__ x2,
                                                int* __restrict__ idx9) {
    __shared__ float avs[4][3 * 64];
    __shared__ int2  vcs[4][3 * 64];
    __shared__ float a9s[4];
    const int tid = threadIdx.x;
    const int wv = tid >> 6, lane = tid & 63;
    const size_t n = (size_t)blockIdx.x * 4 + wv;
    const int b = (int)(n / NN);
    const int nn = (int)(n - (size_t)b * NN);
    const int c0 = cand_cnt[n * 4 + 0];
    const int c1 = cand_cnt[n * 4 + 1];
    const int c2 = cand_cnt[n * 4 + 2];
    const int c3 = cand_cnt[n * 4 + 3];
    const int p1 = c0, p2 = c0 + c1, p3 = c0 + c1 + c2;
    const int ct = p3 + c3;
    const float* hTb = hT + (size_t)b * NN * 96;
    const float* own = hTb + (size_t)nn * 96;
    const float* x2b = x2 + (size_t)b * NN;

    float av[3]; int cjs[3];
#pragma unroll
    for (int t = 0; t < 3; ++t) { av[t] = FLTMAX; cjs[t] = 0x7fffffff; }
#pragma unroll
    for (int t = 0; t < 3; ++t) {
        const int j = lane + 64 * t;
        if (j < ct) {
            const int qq = (j >= p1) + (j >= p2) + (j >= p3);
            const int base = (qq == 0) ? 0 : (qq == 1) ? p1 : (qq == 2) ? p2 : p3;
            const unsigned u = (unsigned)cand_idx[(n * 4 + qq) * CAP + (j - base)];
            av[t] = bf2f((ushort_t)(u >> 16));
            cjs[t] = (int)(u & 0xffffu);
            avs[wv][j] = av[t];
        }
    }
    __syncthreads();
    // approx ranks by (av, slot); unique lane with rank 8 publishes a9
    {
        int ar[3] = {0, 0, 0};
        for (int j2 = 0; j2 < ct; ++j2) {
            const float a2 = avs[wv][j2];
#pragma unroll
            for (int t = 0; t < 3; ++t) {
                const int j = lane + 64 * t;
                ar[t] += (a2 < av[t] || (a2 == av[t] && j2 < j)) ? 1 : 0;
            }
        }
#pragma unroll
        for (int t = 0; t < 3; ++t) {
            const int j = lane + 64 * t;
            if (j < ct && ar[t] == 8) a9s[wv] = av[t];
        }
    }
    __syncthreads();
    const float cutoff = a9s[wv] + PREF_MARGIN;

    // exact rescore of passing candidates; stage (v, cj) in LDS
    float vs[3];
#pragma unroll
    for (int t = 0; t < 3; ++t) {
        vs[t] = FLTMAX;
        const int j = lane + 64 * t;
        if (j < ct) {
            if (av[t] <= cutoff) {
                const int cj = cjs[t];
                const float* cr = hTb + (size_t)cj * 96;
                float dot = 0.f;
#pragma unroll
                for (int i = 0; i < 24; ++i) {
                    float4 rv = *(const float4*)&own[i * 4];
                    float4 cv4 = *(const float4*)&cr[i * 4];
                    dot = fmaf(rv.x, cv4.x, dot);
                    dot = fmaf(rv.y, cv4.y, dot);
                    dot = fmaf(rv.z, cv4.z, dot);
                    dot = fmaf(rv.w, cv4.w, dot);
                }
                vs[t] = fmaf(-2.f, dot, x2b[cj]);
            }
            vcs[wv][j] = make_int2(__float_as_int(vs[t]), cjs[t]);
        }
    }
    __syncthreads();
    // exact ranks by (v, cj); rank < 9 writes ordered idx9 directly
    {
        int er[3] = {0, 0, 0};
        for (int j2 = 0; j2 < ct; ++j2) {
            const int2 pjc = vcs[wv][j2];
            const float v2 = __int_as_float(pjc.x);
#pragma unroll
            for (int t = 0; t < 3; ++t)
                er[t] += (v2 < vs[t] || (v2 == vs[t] && pjc.y < cjs[t])) ? 1 : 0;
        }
        int* dst = idx9 + n * 9;
#pragma unroll
        for (int t = 0; t < 3; ++t) {
            const int j = lane + 64 * t;
            if (j < ct && vs[t] < FLTMAX && er[t] < 9) dst[er[t]] = cjs[t];
        }
    }
}

// ---------------- K5: [U;V] @ h -> acT bf16 (b,n,384); weights fused ---------
__global__ __launch_bounds__(256) void k_ac(const float* __restrict__ h, const float* __restrict__ gw,
                                            const float* __restrict__ gb, ushort_t* __restrict__ acT) {
    __shared__ float sm[96 * 98 + 96 * 64];
    float* wT = sm;
    float* hl = sm + 96 * 98;
    const int tid = threadIdx.x;
    const int n0 = blockIdx.x * 64, ot = blockIdx.y, b = blockIdx.z;
    // rows 0..191 of M = W1 - W2, rows 192..383 = W2  (W=[W1|W2], 192x192)
    for (int i = tid; i < 96 * 96; i += 256) {
        int o = i / 96, c = i - o * 96;
        float v;
        if (ot < 2) {
            const float* gwp = gw + (size_t)(ot * 96 + o) * 192;
            v = gwp[c] - gwp[96 + c];
        } else {
            v = gw[(size_t)((ot - 2) * 96 + o) * 192 + 96 + c];
        }
        wT[c * 98 + o] = v;
    }
    const float* hb = h + (size_t)b * CC * NN;
    for (int i = tid; i < 96 * 64; i += 256) {
        int c = i >> 6, nl = i & 63;
        hl[i] = hb[(size_t)c * NN + n0 + nl];
    }
    __syncthreads();
    const int tr = tid >> 4, tc = tid & 15;
    float acc[6][4];
#pragma unroll
    for (int i = 0; i < 6; ++i)
#pragma unroll
        for (int j = 0; j < 4; ++j) acc[i][j] = 0.f;
#pragma unroll 4
    for (int c = 0; c < 96; ++c) {
        float4 xv = *(const float4*)&hl[c * 64 + tc * 4];
        const float* wp = &wT[c * 98 + tr * 6];
        float2 w01 = *(const float2*)(wp);
        float2 w23 = *(const float2*)(wp + 2);
        float2 w45 = *(const float2*)(wp + 4);
        float wv[6] = {w01.x, w01.y, w23.x, w23.y, w45.x, w45.y};
        float xj[4] = {xv.x, xv.y, xv.z, xv.w};
#pragma unroll
        for (int i = 0; i < 6; ++i)
#pragma unroll
            for (int j = 0; j < 4; ++j) acc[i][j] = fmaf(wv[i], xj[j], acc[i][j]);
    }
    const int obase = ot * 96 + tr * 6;
    float bs[6];
#pragma unroll
    for (int i = 0; i < 6; ++i) bs[i] = (ot < 2) ? gb[obase + i] : 0.f;
#pragma unroll
    for (int j = 0; j < 4; ++j) {
        ushort_t* dst = acT + ((size_t)b * NN + n0 + tc * 4 + j) * 384 + obase;
        ushort2 p0, p1, p2;
        p0.x = f2bf(acc[0][j] + bs[0]); p0.y = f2bf(acc[1][j] + bs[1]);
        p1.x = f2bf(acc[2][j] + bs[2]); p1.y = f2bf(acc[3][j] + bs[3]);
        p2.x = f2bf(acc[4][j] + bs[4]); p2.y = f2bf(acc[5][j] + bs[5]);
        *(ushort2*)(dst + 0) = p0;
        *(ushort2*)(dst + 2) = p1;
        *(ushort2*)(dst + 4) = p2;
    }
}

// ---------------- K6: gather neighbors (bf16), k-max, relu -> gT fp32 --------
__global__ __launch_bounds__(256) void k_gather(const ushort_t* __restrict__ acT,
                                                const int* __restrict__ idx9,
                                                float* __restrict__ gT) {
    const int lane = threadIdx.x & 63;
    const int wv = threadIdx.x >> 6;
    const int b = blockIdx.y;
    const int nb = blockIdx.x * 16 + wv * 4;
    for (int r = 0; r < 4; ++r) {
        const int n = nb + r;
        const ushort_t* ar = acT + ((size_t)b * NN + n) * 384;
        float a0 = bf2f(ar[lane]), a1 = bf2f(ar[lane + 64]), a2 = bf2f(ar[lane + 128]);
        const int* ip = idx9 + ((size_t)b * NN + n) * 9;
        int jj[9];
#pragma unroll
        for (int k = 0; k < 9; ++k) jj[k] = ip[k];
        float m0 = -FLTMAX, m1 = -FLTMAX, m2 = -FLTMAX;
#pragma unroll
        for (int k = 0; k < 9; ++k) {
            const ushort_t* cr = acT + ((size_t)b * NN + jj[k]) * 384 + 192;
            m0 = fmaxf(m0, a0 + bf2f(cr[lane]));
            m1 = fmaxf(m1, a1 + bf2f(cr[lane + 64]));
            m2 = fmaxf(m2, a2 + bf2f(cr[lane + 128]));
        }
        float* gr = gT + ((size_t)b * NN + n) * 192;
        gr[lane] = fmaxf(m0, 0.f);
        gr[lane + 64] = fmaxf(m1, 0.f);
        gr[lane + 128] = fmaxf(m2, 0.f);
    }
}

// ---------------- K7: fc2 (NT gemm, 16-col tiles) -> out + mean/max ----------
// grid (196, BB): 16 cols/block, 96 out-ch; thread (tr,tc) owns 6 ch x 1 col.
__global__ __launch_bounds__(256) void k_fc2(const float* __restrict__ gT, const float* __restrict__ w,
                                             const float* __restrict__ bias, float* __restrict__ out,
                                             float* __restrict__ sa_in) {
    __shared__ float Wc[96 * 36];
    __shared__ float Gc[16 * 36];
    __shared__ float red[2][16][17];
    const int tid = threadIdx.x;
    const int n0 = blockIdx.x * 16, b = blockIdx.y;
    const int tr = tid >> 4, tc = tid & 15;
    float acc[6];
#pragma unroll
    for (int i = 0; i < 6; ++i) acc[i] = 0.f;
    for (int kc = 0; kc < 192; kc += 32) {
        for (int i = tid; i < 96 * 32; i += 256) {
            int c = i >> 5, k = i & 31;
            Wc[c * 36 + k] = w[(size_t)c * 192 + kc + k];
        }
        for (int i = tid; i < 16 * 32; i += 256) {
            int nl = i >> 5, k = i & 31;
            Gc[nl * 36 + k] = gT[((size_t)b * NN + n0 + nl) * 192 + kc + k];
        }
        __syncthreads();
#pragma unroll
        for (int k = 0; k < 32; k += 4) {
            float4 gv = *(const float4*)&Gc[tc * 36 + k];
#pragma unroll
            for (int i = 0; i < 6; ++i) {
                float4 wv = *(const float4*)&Wc[(tr * 6 + i) * 36 + k];
                acc[i] = fmaf(wv.x, gv.x, acc[i]);
                acc[i] = fmaf(wv.y, gv.y, acc[i]);
                acc[i] = fmaf(wv.z, gv.z, acc[i]);
                acc[i] = fmaf(wv.w, gv.w, acc[i]);
            }
        }
        __syncthreads();
    }
    float* ob = out + (size_t)b * CC * NN;
    float ps = 0.f, pm = -FLTMAX;
#pragma unroll
    for (int i = 0; i < 6; ++i) {
        float o = acc[i] + bias[tr * 6 + i];
        ob[(size_t)(tr * 6 + i) * NN + n0 + tc] = o;
        ps += o;
        pm = fmaxf(pm, o);
    }
    red[0][tr][tc] = ps;
    red[1][tr][tc] = pm;
    __syncthreads();
    if (tid < 16) {
        float s_ = 0.f, m_ = -FLTMAX;
#pragma unroll
        for (int t = 0; t < 16; ++t) { s_ += red[0][t][tid]; m_ = fmaxf(m_, red[1][t][tid]); }
        sa_in[(size_t)b * 2 * NN + n0 + tid] = s_ * (1.0f / 96.0f);
        sa_in[(size_t)b * 2 * NN + NN + n0 + tid] = m_;
    }
}

// ---------------- K9: 7x7 conv + sigmoid + out*att + shortcut (in place) -----
__global__ __launch_bounds__(256) void k_att(const float* __restrict__ sa_in, const float* __restrict__ sw,
                                             const float* __restrict__ x, float* __restrict__ out) {
    int n = blockIdx.x * 256 + threadIdx.x;
    int b = blockIdx.y;
    if (n >= NN) return;
    int y = n / 56, xw = n - y * 56;
    float acc = 0.f;
#pragma unroll
    for (int ci = 0; ci < 2; ++ci) {
        const float* sb = sa_in + ((size_t)b * 2 + ci) * NN;
#pragma unroll
        for (int dy = 0; dy < 7; ++dy) {
            int yy = y + dy - 3;
            if ((unsigned)yy < 56u) {
#pragma unroll
                for (int dx = 0; dx < 7; ++dx) {
                    int xx = xw + dx - 3;
                    if ((unsigned)xx < 56u)
                        acc = fmaf(sb[yy * 56 + xx], sw[(ci * 7 + dy) * 7 + dx], acc);
                }
            }
        }
    }
    float att = 1.f / (1.f + expf(-acc));
    const float* xb = x + (size_t)b * CC * NN + n;
    float* ob = out + (size_t)b * CC * NN + n;
#pragma unroll 4
    for (int c = 0; c < 96; ++c) {
        size_t o = (size_t)c * NN;
        ob[o] = fmaf(ob[o], att, xb[o]);
    }
}

extern "C" void kernel_launch(void* const* d_in, const int* in_sizes, int n_in,
                              void* d_out, int out_size, void* d_ws, size_t ws_size,
                              hipStream_t stream) {
    (void)in_sizes; (void)n_in; (void)out_size; (void)ws_size;
    const float* x       = (const float*)d_in[0];
    const float* fc1_w   = (const float*)d_in[1];
    const float* fc1_b   = (const float*)d_in[2];
    const float* gconv_w = (const float*)d_in[3];
    const float* gconv_b = (const float*)d_in[4];
    const float* fc2_w   = (const float*)d_in[5];
    const float* fc2_b   = (const float*)d_in[6];
    const float* sa_w    = (const float*)d_in[7];
    float* out = (float*)d_out;

    // workspace layout (floats)
    float* ws   = (float*)d_ws;
    float* h    = ws;                                   // 1,204,224
    float* x2   = h + (size_t)BB * CC * NN;             // 12,544
    int*   idx9 = (int*)(x2 + BB * NN);                 // 112,896 ints
    float* regA = (float*)(idx9 + (size_t)BB * NN * 9); // 2,408,448 fl overlay:
    //   k_fc1->k_dist: hAhi (first half) ; k_ac->k_gather: acT bf16 (full)
    ushort_t* hAhi = (ushort_t*)regA;                   // 2,408,448 ushorts
    ushort_t* acT  = (ushort_t*)regA;                   // 4,816,896 ushorts
    float* hT   = regA + 2408448;                       // 1,204,224 fl
    float* regB = hT + 1204224;                         // 2,408,448 fl overlay:
    //   k_dist->k_merge9: cand_idx (BB*NN*4*CAP=2,207,744 ints) + cand_cnt
    //   k_gather->k_fc2: gT
    int*   cand_idx = (int*)regB;
    int*   cand_cnt = (int*)(regB + 2207744);           // BB*NN*4 = 50,176 ints
    float* gT   = regB;                                 // 2,408,448 fl
    float* sa_in = regB + 2408448;                      // 25,088 fl

    k_fc1   <<<dim3(49, BB), 256, 0, stream>>>(x, fc1_w, fc1_b, h, x2, hAhi, hT);
    k_dist  <<<dim3(98, 4, BB), 256, 0, stream>>>(hAhi, x2, cand_cnt, cand_idx);
    k_merge9<<<dim3(3136), 256, 0, stream>>>(cand_cnt, cand_idx, hT, x2, idx9);
    k_ac    <<<dim3(49, 4, BB), 256, 0, stream>>>(h, gconv_w, gconv_b, acT);
    k_gather<<<dim3(196, BB), 256, 0, stream>>>(acT, idx9, gT);
    k_fc2   <<<dim3(196, BB), 256, 0, stream>>>(gT, fc2_w, fc2_b, out, sa_in);
    k_att   <<<dim3(13, BB), 256, 0, stream>>>(sa_in, sa_w, x, out);
}

// Round 17
// 248.217 us; speedup vs baseline: 1.0636x; 1.0636x over previous
//
#include <hip/hip_runtime.h>

#define BB 4
#define CC 96
#define NN 3136
#define FLTMAX 3.402823466e+38f
#define CAP 44
#define DELTA 1.0f

typedef unsigned short ushort_t;
typedef __attribute__((ext_vector_type(8))) short bf16x8;
typedef __attribute__((ext_vector_type(4))) float f32x4;

// fp32 -> bf16 round-to-nearest-even
__device__ __forceinline__ ushort_t f2bf(float f) {
    unsigned u = __float_as_uint(f);
    unsigned r = (u + 0x7fff + ((u >> 16) & 1)) >> 16;
    return (ushort_t)r;
}
__device__ __forceinline__ float bf2f(ushort_t us) {
    return __uint_as_float(((unsigned)us) << 16);
}

// htile layout (per batch):
//   idx(n,c) = (((n>>5)*12 + (c>>3))*32 + (n&31))*8 + (c&7)

// ---------------- K1: fc1 -> h (b,c,n) + x2 + bf16 htile (hi only) + hT ------
__global__ __launch_bounds__(256) void k_fc1(const float* __restrict__ x, const float* __restrict__ w,
                                             const float* __restrict__ bias, float* __restrict__ h,
                                             float* __restrict__ x2g,
                                             ushort_t* __restrict__ hAhi,
                                             float* __restrict__ hT) {
    __shared__ float sm[96 * 98 + 96 * 64];
    float* wT = sm;              // [c][o] pad 98
    float* xl = sm + 96 * 98;    // [c][64]
    const int tid = threadIdx.x;
    const int n0 = blockIdx.x * 64;
    const int b = blockIdx.y;
    for (int i = tid; i < 96 * 96; i += 256) {
        int o = i / 96, c = i - o * 96;
        wT[c * 98 + o] = w[i];
    }
    const float* xb = x + (size_t)b * CC * NN;
    for (int i = tid; i < 96 * 64; i += 256) {
        int c = i >> 6, nl = i & 63;
        xl[i] = xb[(size_t)c * NN + n0 + nl];
    }
    __syncthreads();
    const int tr = tid >> 4, tc = tid & 15;
    float acc[6][4];
#pragma unroll
    for (int i = 0; i < 6; ++i)
#pragma unroll
        for (int j = 0; j < 4; ++j) acc[i][j] = 0.f;
#pragma unroll 4
    for (int c = 0; c < 96; ++c) {
        float4 xv = *(const float4*)&xl[c * 64 + tc * 4];
        const float* wp = &wT[c * 98 + tr * 6];
        float2 w01 = *(const float2*)(wp);
        float2 w23 = *(const float2*)(wp + 2);
        float2 w45 = *(const float2*)(wp + 4);
        float wv[6] = {w01.x, w01.y, w23.x, w23.y, w45.x, w45.y};
        float xj[4] = {xv.x, xv.y, xv.z, xv.w};
#pragma unroll
        for (int i = 0; i < 6; ++i)
#pragma unroll
            for (int j = 0; j < 4; ++j) acc[i][j] = fmaf(wv[i], xj[j], acc[i][j]);
    }
    float* hb = h + (size_t)b * CC * NN;
    float* hTb = hT + (size_t)b * NN * 96;
    ushort_t* thi = hAhi + (size_t)b * 602112;
#pragma unroll
    for (int i = 0; i < 6; ++i) {
        float bi = bias[tr * 6 + i];
        acc[i][0] += bi; acc[i][1] += bi; acc[i][2] += bi; acc[i][3] += bi;
        float4 o4 = make_float4(acc[i][0], acc[i][1], acc[i][2], acc[i][3]);
        *(float4*)&hb[(size_t)(tr * 6 + i) * NN + n0 + tc * 4] = o4;
        const int c = tr * 6 + i;
        const int cpart = c >> 3;   // 12 parts of 8 channels
#pragma unroll
        for (int j = 0; j < 4; ++j) {
            const int n = n0 + tc * 4 + j;
            const int idx = (((n >> 5) * 12 + cpart) * 32 + (n & 31)) * 8 + (c & 7);
            thi[idx] = f2bf(acc[i][j]);
            hTb[(size_t)n * 96 + c] = acc[i][j];
        }
    }
    __syncthreads();   // wT/xl reads done -> reuse sm[0..1024) for x2 partials
#pragma unroll
    for (int j = 0; j < 4; ++j) {
        float s = 0.f;
#pragma unroll
        for (int i = 0; i < 6; ++i) s = fmaf(acc[i][j], acc[i][j], s);
        sm[tr * 64 + tc * 4 + j] = s;
    }
    __syncthreads();
    if (tid < 64) {
        float s = 0.f;
#pragma unroll
        for (int t = 0; t < 16; ++t) s += sm[t * 64 + tid];
        x2g[(size_t)b * NN + n0 + tid] = s;
    }
}

// hi-only MFMA tile body: 12 loads, 12 MFMA
#define MFMA_TILE_HI(t, acc0, acc1, acc2, acc3)                                       \
    {                                                                                 \
        const int abase_ = (t) * 6144;                                                \
        _Pragma("unroll")                                                             \
        for (int ks_ = 0; ks_ < 3; ++ks_) {                                           \
            const int base_ = abase_ + ks_ * 1024;                                    \
            bf16x8 a0_ = *(const bf16x8*)(hHi + base_ + aoff0);                       \
            bf16x8 a1_ = *(const bf16x8*)(hHi + base_ + aoff1);                       \
            bf16x8 a2_ = *(const bf16x8*)(hHi + base_ + 3072 + aoff0);                \
            bf16x8 a3_ = *(const bf16x8*)(hHi + base_ + 3072 + aoff1);                \
            acc0 = __builtin_amdgcn_mfma_f32_16x16x32_bf16(a0_, bhi[ks_], acc0, 0, 0, 0); \
            acc1 = __builtin_amdgcn_mfma_f32_16x16x32_bf16(a1_, bhi[ks_], acc1, 0, 0, 0); \
            acc2 = __builtin_amdgcn_mfma_f32_16x16x32_bf16(a2_, bhi[ks_], acc2, 0, 0, 0); \
            acc3 = __builtin_amdgcn_mfma_f32_16x16x32_bf16(a3_, bhi[ks_], acc3, 0, 0, 0); \
        }                                                                             \
    }

// ---------------- K3: threshold KNN filter, hi-only + reg score cache --------
// grid (98 n-blocks of 32, 4 m-quarters, B), 256 thr = 4 waves.
// Phase A: hi.hi approx scores; per-lane branchless top-3 (fp32); scores cached
//          in registers as packed bf16.
// thr[row][q] = exact 9th-smallest of staged 24 fp32 values + DELTA (stored for
//               k_merge9's cutoff = min_q thr).
// Phase B: unpack cached scores, emit (bf16score<<16|m) for all <= thr.
__global__ __launch_bounds__(256) void k_dist(const ushort_t* __restrict__ hAhi,
                                              const float* __restrict__ x2,
                                              int* __restrict__ cand_cnt,
                                              int* __restrict__ cand_idx,
                                              float* __restrict__ thr_row) {
    __shared__ float thrb[32][24];
    __shared__ float thr_s[32];
    __shared__ int   cnt[32];
    __shared__ int   list[32][CAP];
    const int tid = threadIdx.x;
    const int nb = blockIdx.x, q = blockIdx.y, b = blockIdx.z;
    const int w = tid >> 6, l = tid & 63;
    const int ln = l & 15, lq = l >> 4;
    const int p = w >> 1;
    const int kl_off = lq * 256;
    const ushort_t* hHi = hAhi + (size_t)b * 602112;
    const float* x2b = x2 + (size_t)b * NN;

    const int lane32n = (w & 1) * 16 + ln;
    bf16x8 bhi[3];
#pragma unroll
    for (int ks = 0; ks < 3; ++ks) {
        const int off = nb * 3072 + ks * 1024 + kl_off + lane32n * 8;
        bhi[ks] = *(const bf16x8*)(hHi + off);
    }
    const int aoff0 = kl_off + ln * 8;
    const int aoff1 = kl_off + (16 + ln) * 8;

    // quarter boundaries over 49 tiles: {0,13,25,37,49}
    const int qb0 = (q == 0) ? 0 : (q == 1) ? 13 : (q == 2) ? 25 : 37;
    const int qb1 = (q == 0) ? 13 : (q == 1) ? 25 : (q == 2) ? 37 : 49;
    const int tstart = qb0 + p;

    unsigned scache[7][8];   // packed bf16 scores: [tile][msub*2 + pair]
    // ---- Phase A ----
    float lv0 = FLTMAX, lv1 = FLTMAX, lv2 = FLTMAX;
#pragma unroll
    for (int ti = 0; ti < 7; ++ti) {
        const int t = tstart + 2 * ti;
        if (t < qb1) {
            const int m0 = t * 64;
            f32x4 acc0 = {0.f, 0.f, 0.f, 0.f}, acc1 = {0.f, 0.f, 0.f, 0.f};
            f32x4 acc2 = {0.f, 0.f, 0.f, 0.f}, acc3 = {0.f, 0.f, 0.f, 0.f};
            MFMA_TILE_HI(t, acc0, acc1, acc2, acc3);
#pragma unroll
            for (int msub = 0; msub < 4; ++msub) {
                f32x4 a = (msub == 0) ? acc0 : (msub == 1) ? acc1 : (msub == 2) ? acc2 : acc3;
                const int mb = m0 + msub * 16 + lq * 4;
                float4 xv = *(const float4*)&x2b[mb];
                float s0 = fmaf(-2.f, a[0], xv.x);
                float s1 = fmaf(-2.f, a[1], xv.y);
                float s2 = fmaf(-2.f, a[2], xv.z);
                float s3 = fmaf(-2.f, a[3], xv.w);
                scache[ti][msub * 2 + 0] = ((unsigned)f2bf(s0) << 16) | (unsigned)f2bf(s1);
                scache[ti][msub * 2 + 1] = ((unsigned)f2bf(s2) << 16) | (unsigned)f2bf(s3);
                float ss[4] = {s0, s1, s2, s3};
#pragma unroll
                for (int r = 0; r < 4; ++r) {
                    float v = ss[r];
                    float t0 = fminf(lv0, v);
                    lv0 = fmaxf(t0, lv1);
                    float t1 = fminf(t0, lv1);
                    lv1 = fmaxf(t1, lv2);
                    lv2 = fminf(t1, lv2);
                }
            }
        }
    }
    {
        const int sidx = (p * 4 + lq) * 3;
        thrb[lane32n][sidx + 0] = lv0;
        thrb[lane32n][sidx + 1] = lv1;
        thrb[lane32n][sidx + 2] = lv2;
    }
    __syncthreads();
    if (tid < 32) {
        float tmp[24];
#pragma unroll
        for (int j = 0; j < 24; ++j) tmp[j] = thrb[tid][j];
        float last = FLTMAX;
        for (int kk = 0; kk < 9; ++kk) {
            float mn = FLTMAX; int ms = 0;
            for (int j = 0; j < 24; ++j)
                if (tmp[j] < mn) { mn = tmp[j]; ms = j; }
            tmp[ms] = FLTMAX;
            last = mn;
        }
        thr_s[tid] = last + DELTA;
        cnt[tid] = 0;
        thr_row[((size_t)b * NN + nb * 32 + tid) * 4 + q] = last + DELTA;
    }
    __syncthreads();
    const float thr = thr_s[lane32n];

    // ---- Phase B: scan cached scores, emit all <= thr (no loads/MFMA) ----
#pragma unroll
    for (int ti = 0; ti < 7; ++ti) {
        const int t = tstart + 2 * ti;
        if (t < qb1) {
            const int m0 = t * 64;
#pragma unroll
            for (int msub = 0; msub < 4; ++msub) {
                const int mb = m0 + msub * 16 + lq * 4;
                const unsigned u01 = scache[ti][msub * 2 + 0];
                const unsigned u23 = scache[ti][msub * 2 + 1];
                unsigned bits[4] = {u01 >> 16, u01 & 0xffffu, u23 >> 16, u23 & 0xffffu};
#pragma unroll
                for (int r = 0; r < 4; ++r) {
                    if (bf2f((ushort_t)bits[r]) <= thr) {
                        int pos = atomicAdd(&cnt[lane32n], 1);
                        if (pos < CAP) list[lane32n][pos] = (int)((bits[r] << 16) | (unsigned)(mb + r));
                    }
                }
            }
        }
    }
    __syncthreads();
    // writeout
    const size_t rowbase = (size_t)b * NN + nb * 32;
    if (tid < 32) cand_cnt[(rowbase + tid) * 4 + q] = min(cnt[tid], CAP);
    for (int i = tid; i < 32 * CAP; i += 256) {
        int r = i / CAP, j = i - r * CAP;
        if (j < min(cnt[r], CAP))
            cand_idx[((rowbase + r) * 4 + q) * CAP + j] = list[r][j];
    }
}

// ---------------- K4: min-thr cutoff + compact + count-rank -> idx9 ----------
// grid 3136 blocks x 256 thr = 4 waves; one wave per row n.
// cutoff = min_q thr_row[n][q] (valid: every row-top-9 member's approx <= every
// quarter's thr, since DELTA >= 2*approx-error). Exact-rescore passing
// candidates (~25, >=9 guaranteed), compact (v,cj) to per-wave LDS list
// (set-deterministic), rank-by-counting over npw entries -> ordered idx9.
__global__ __launch_bounds__(256) void k_merge9(const int* __restrict__ cand_cnt,
                                                const int* __restrict__ cand_idx,
                                                const float* __restrict__ thr_row,
                                                const float* __restrict__ hT,
                                                const float* __restrict__ x2,
                                                int* __restrict__ idx9) {
    __shared__ int  np[4];
    __shared__ int2 pl[4][192];
    const int tid = threadIdx.x;
    const int wv = tid >> 6, lane = tid & 63;
    const size_t n = (size_t)blockIdx.x * 4 + wv;
    const int b = (int)(n / NN);
    const int nn = (int)(n - (size_t)b * NN);
    const int c0 = cand_cnt[n * 4 + 0];
    const int c1 = cand_cnt[n * 4 + 1];
    const int c2 = cand_cnt[n * 4 + 2];
    const int c3 = cand_cnt[n * 4 + 3];
    const int p1 = c0, p2 = c0 + c1, p3 = c0 + c1 + c2;
    const int ct = p3 + c3;
    const float cutoff = fminf(fminf(thr_row[n * 4 + 0], thr_row[n * 4 + 1]),
                               fminf(thr_row[n * 4 + 2], thr_row[n * 4 + 3]));
    if (lane == 0) np[wv] = 0;   // wave-lockstep: visible to the wave's later ops
    const float* hTb = hT + (size_t)b * NN * 96;
    const float* own = hTb + (size_t)nn * 96;
    const float* x2b = x2 + (size_t)b * NN;
#pragma unroll
    for (int t = 0; t < 3; ++t) {
        const int j = lane + 64 * t;
        if (j < ct) {
            const int qq = (j >= p1) + (j >= p2) + (j >= p3);
            const int base = (qq == 0) ? 0 : (qq == 1) ? p1 : (qq == 2) ? p2 : p3;
            const unsigned u = (unsigned)cand_idx[(n * 4 + qq) * CAP + (j - base)];
            const float av = bf2f((ushort_t)(u >> 16));
            if (av <= cutoff) {
                const int cj = (int)(u & 0xffffu);
                const float* cr = hTb + (size_t)cj * 96;
                float dot = 0.f;
#pragma unroll
                for (int i = 0; i < 24; ++i) {
                    float4 rv = *(const float4*)&own[i * 4];
                    float4 cv4 = *(const float4*)&cr[i * 4];
                    dot = fmaf(rv.x, cv4.x, dot);
                    dot = fmaf(rv.y, cv4.y, dot);
                    dot = fmaf(rv.z, cv4.z, dot);
                    dot = fmaf(rv.w, cv4.w, dot);
                }
                const float v = fmaf(-2.f, dot, x2b[cj]);
                const int pos = atomicAdd(&np[wv], 1);
                pl[wv][pos] = make_int2(__float_as_int(v), cj);
            }
        }
    }
    const int npw = np[wv];
    int2 mine[3]; int rk[3];
#pragma unroll
    for (int t = 0; t < 3; ++t) {
        const int s = lane + 64 * t;
        mine[t] = (s < npw) ? pl[wv][s] : make_int2(0x7f7fffff, 0x7fffffff);
        rk[t] = 0;
    }
    for (int j2 = 0; j2 < npw; ++j2) {
        const int2 e = pl[wv][j2];
        const float ev = __int_as_float(e.x);
#pragma unroll
        for (int t = 0; t < 3; ++t) {
            const float mv = __int_as_float(mine[t].x);
            rk[t] += (ev < mv || (ev == mv && e.y < mine[t].y)) ? 1 : 0;
        }
    }
    int* dst = idx9 + n * 9;
#pragma unroll
    for (int t = 0; t < 3; ++t) {
        const int s = lane + 64 * t;
        if (s < npw && rk[t] < 9) dst[rk[t]] = mine[t].y;
    }
}

// ---------------- K5: [U;V] @ h -> acT bf16 (b,n,384); weights fused ---------
__global__ __launch_bounds__(256) void k_ac(const float* __restrict__ h, const float* __restrict__ gw,
                                            const float* __restrict__ gb, ushort_t* __restrict__ acT) {
    __shared__ float sm[96 * 98 + 96 * 64];
    float* wT = sm;
    float* hl = sm + 96 * 98;
    const int tid = threadIdx.x;
    const int n0 = blockIdx.x * 64, ot = blockIdx.y, b = blockIdx.z;
    // rows 0..191 of M = W1 - W2, rows 192..383 = W2  (W=[W1|W2], 192x192)
    for (int i = tid; i < 96 * 96; i += 256) {
        int o = i / 96, c = i - o * 96;
        float v;
        if (ot < 2) {
            const float* gwp = gw + (size_t)(ot * 96 + o) * 192;
            v = gwp[c] - gwp[96 + c];
        } else {
            v = gw[(size_t)((ot - 2) * 96 + o) * 192 + 96 + c];
        }
        wT[c * 98 + o] = v;
    }
    const float* hb = h + (size_t)b * CC * NN;
    for (int i = tid; i < 96 * 64; i += 256) {
        int c = i >> 6, nl = i & 63;
        hl[i] = hb[(size_t)c * NN + n0 + nl];
    }
    __syncthreads();
    const int tr = tid >> 4, tc = tid & 15;
    float acc[6][4];
#pragma unroll
    for (int i = 0; i < 6; ++i)
#pragma unroll
        for (int j = 0; j < 4; ++j) acc[i][j] = 0.f;
#pragma unroll 4
    for (int c = 0; c < 96; ++c) {
        float4 xv = *(const float4*)&hl[c * 64 + tc * 4];
        const float* wp = &wT[c * 98 + tr * 6];
        float2 w01 = *(const float2*)(wp);
        float2 w23 = *(const float2*)(wp + 2);
        float2 w45 = *(const float2*)(wp + 4);
        float wv[6] = {w01.x, w01.y, w23.x, w23.y, w45.x, w45.y};
        float xj[4] = {xv.x, xv.y, xv.z, xv.w};
#pragma unroll
        for (int i = 0; i < 6; ++i)
#pragma unroll
            for (int j = 0; j < 4; ++j) acc[i][j] = fmaf(wv[i], xj[j], acc[i][j]);
    }
    const int obase = ot * 96 + tr * 6;
    float bs[6];
#pragma unroll
    for (int i = 0; i < 6; ++i) bs[i] = (ot < 2) ? gb[obase + i] : 0.f;
#pragma unroll
    for (int j = 0; j < 4; ++j) {
        ushort_t* dst = acT + ((size_t)b * NN + n0 + tc * 4 + j) * 384 + obase;
        ushort2 p0, p1, p2;
        p0.x = f2bf(acc[0][j] + bs[0]); p0.y = f2bf(acc[1][j] + bs[1]);
        p1.x = f2bf(acc[2][j] + bs[2]); p1.y = f2bf(acc[3][j] + bs[3]);
        p2.x = f2bf(acc[4][j] + bs[4]); p2.y = f2bf(acc[5][j] + bs[5]);
        *(ushort2*)(dst + 0) = p0;
        *(ushort2*)(dst + 2) = p1;
        *(ushort2*)(dst + 4) = p2;
    }
}

// ---------------- K6: gather neighbors (bf16), k-max, relu -> gT fp32 --------
__global__ __launch_bounds__(256) void k_gather(const ushort_t* __restrict__ acT,
                                                const int* __restrict__ idx9,
                                                float* __restrict__ gT) {
    const int lane = threadIdx.x & 63;
    const int wv = threadIdx.x >> 6;
    const int b = blockIdx.y;
    const int nb = blockIdx.x * 16 + wv * 4;
    for (int r = 0; r < 4; ++r) {
        const int n = nb + r;
        const ushort_t* ar = acT + ((size_t)b * NN + n) * 384;
        float a0 = bf2f(ar[lane]), a1 = bf2f(ar[lane + 64]), a2 = bf2f(ar[lane + 128]);
        const int* ip = idx9 + ((size_t)b * NN + n) * 9;
        int jj[9];
#pragma unroll
        for (int k = 0; k < 9; ++k) jj[k] = ip[k];
        float m0 = -FLTMAX, m1 = -FLTMAX, m2 = -FLTMAX;
#pragma unroll
        for (int k = 0; k < 9; ++k) {
            const ushort_t* cr = acT + ((size_t)b * NN + jj[k]) * 384 + 192;
            m0 = fmaxf(m0, a0 + bf2f(cr[lane]));
            m1 = fmaxf(m1, a1 + bf2f(cr[lane + 64]));
            m2 = fmaxf(m2, a2 + bf2f(cr[lane + 128]));
        }
        float* gr = gT + ((size_t)b * NN + n) * 192;
        gr[lane] = fmaxf(m0, 0.f);
        gr[lane + 64] = fmaxf(m1, 0.f);
        gr[lane + 128] = fmaxf(m2, 0.f);
    }
}

// ---------------- K7: fc2 (NT gemm, 16-col tiles) -> out + mean/max ----------
// grid (196, BB): 16 cols/block, 96 out-ch; thread (tr,tc) owns 6 ch x 1 col.
__global__ __launch_bounds__(256) void k_fc2(const float* __restrict__ gT, const float* __restrict__ w,
                                             const float* __restrict__ bias, float* __restrict__ out,
                                             float* __restrict__ sa_in) {
    __shared__ float Wc[96 * 36];
    __shared__ float Gc[16 * 36];
    __shared__ float red[2][16][17];
    const int tid = threadIdx.x;
    const int n0 = blockIdx.x * 16, b = blockIdx.y;
    const int tr = tid >> 4, tc = tid & 15;
    float acc[6];
#pragma unroll
    for (int i = 0; i < 6; ++i) acc[i] = 0.f;
    for (int kc = 0; kc < 192; kc += 32) {
        for (int i = tid; i < 96 * 32; i += 256) {
            int c = i >> 5, k = i & 31;
            Wc[c * 36 + k] = w[(size_t)c * 192 + kc + k];
        }
        for (int i = tid; i < 16 * 32; i += 256) {
            int nl = i >> 5, k = i & 31;
            Gc[nl * 36 + k] = gT[((size_t)b * NN + n0 + nl) * 192 + kc + k];
        }
        __syncthreads();
#pragma unroll
        for (int k = 0; k < 32; k += 4) {
            float4 gv = *(const float4*)&Gc[tc * 36 + k];
#pragma unroll
            for (int i = 0; i < 6; ++i) {
                float4 wv = *(const float4*)&Wc[(tr * 6 + i) * 36 + k];
                acc[i] = fmaf(wv.x, gv.x, acc[i]);
                acc[i] = fmaf(wv.y, gv.y, acc[i]);
                acc[i] = fmaf(wv.z, gv.z, acc[i]);
                acc[i] = fmaf(wv.w, gv.w, acc[i]);
            }
        }
        __syncthreads();
    }
    float* ob = out + (size_t)b * CC * NN;
    float ps = 0.f, pm = -FLTMAX;
#pragma unroll
    for (int i = 0; i < 6; ++i) {
        float o = acc[i] + bias[tr * 6 + i];
        ob[(size_t)(tr * 6 + i) * NN + n0 + tc] = o;
        ps += o;
        pm = fmaxf(pm, o);
    }
    red[0][tr][tc] = ps;
    red[1][tr][tc] = pm;
    __syncthreads();
    if (tid < 16) {
        float s_ = 0.f, m_ = -FLTMAX;
#pragma unroll
        for (int t = 0; t < 16; ++t) { s_ += red[0][t][tid]; m_ = fmaxf(m_, red[1][t][tid]); }
        sa_in[(size_t)b * 2 * NN + n0 + tid] = s_ * (1.0f / 96.0f);
        sa_in[(size_t)b * 2 * NN + NN + n0 + tid] = m_;
    }
}

// ---------------- K9: 7x7 conv + sigmoid + out*att + shortcut (in place) -----
__global__ __launch_bounds__(256) void k_att(const float* __restrict__ sa_in, const float* __restrict__ sw,
                                             const float* __restrict__ x, float* __restrict__ out) {
    int n = blockIdx.x * 256 + threadIdx.x;
    int b = blockIdx.y;
    if (n >= NN) return;
    int y = n / 56, xw = n - y * 56;
    float acc = 0.f;
#pragma unroll
    for (int ci = 0; ci < 2; ++ci) {
        const float* sb = sa_in + ((size_t)b * 2 + ci) * NN;
#pragma unroll
        for (int dy = 0; dy < 7; ++dy) {
            int yy = y + dy - 3;
            if ((unsigned)yy < 56u) {
#pragma unroll
                for (int dx = 0; dx < 7; ++dx) {
                    int xx = xw + dx - 3;
                    if ((unsigned)xx < 56u)
                        acc = fmaf(sb[yy * 56 + xx], sw[(ci * 7 + dy) * 7 + dx], acc);
                }
            }
        }
    }
    float att = 1.f / (1.f + expf(-acc));
    const float* xb = x + (size_t)b * CC * NN + n;
    float* ob = out + (size_t)b * CC * NN + n;
#pragma unroll 4
    for (int c = 0; c < 96; ++c) {
        size_t o = (size_t)c * NN;
        ob[o] = fmaf(ob[o], att, xb[o]);
    }
}

extern "C" void kernel_launch(void* const* d_in, const int* in_sizes, int n_in,
                              void* d_out, int out_size, void* d_ws, size_t ws_size,
                              hipStream_t stream) {
    (void)in_sizes; (void)n_in; (void)out_size; (void)ws_size;
    const float* x       = (const float*)d_in[0];
    const float* fc1_w   = (const float*)d_in[1];
    const float* fc1_b   = (const float*)d_in[2];
    const float* gconv_w = (const float*)d_in[3];
    const float* gconv_b = (const float*)d_in[4];
    const float* fc2_w   = (const float*)d_in[5];
    const float* fc2_b   = (const float*)d_in[6];
    const float* sa_w    = (const float*)d_in[7];
    float* out = (float*)d_out;

    // workspace layout (floats)
    float* ws   = (float*)d_ws;
    float* h    = ws;                                   // 1,204,224
    float* x2   = h + (size_t)BB * CC * NN;             // 12,544
    int*   idx9 = (int*)(x2 + BB * NN);                 // 112,896 ints
    float* regA = (float*)(idx9 + (size_t)BB * NN * 9); // 2,408,448 fl overlay:
    //   k_fc1->k_dist: hAhi (first half) ; k_ac->k_gather: acT bf16 (full)
    ushort_t* hAhi = (ushort_t*)regA;                   // 2,408,448 ushorts
    ushort_t* acT  = (ushort_t*)regA;                   // 4,816,896 ushorts
    float* hT   = regA + 2408448;                       // 1,204,224 fl
    float* regB = hT + 1204224;                         // 2,408,448 fl overlay:
    //   k_dist->k_merge9: cand_idx + cand_cnt + thr_row ; k_gather->k_fc2: gT
    int*   cand_idx = (int*)regB;                       // BB*NN*4*CAP = 2,207,744
    int*   cand_cnt = (int*)(regB + 2207744);           // BB*NN*4 = 50,176
    float* thr_row  = regB + 2207744 + 50176;           // BB*NN*4 = 50,176
    float* gT   = regB;                                 // 2,408,448 fl
    float* sa_in = regB + 2408448;                      // 25,088 fl

    k_fc1   <<<dim3(49, BB), 256, 0, stream>>>(x, fc1_w, fc1_b, h, x2, hAhi, hT);
    k_dist  <<<dim3(98, 4, BB), 256, 0, stream>>>(hAhi, x2, cand_cnt, cand_idx, thr_row);
    k_merge9<<<dim3(3136), 256, 0, stream>>>(cand_cnt, cand_idx, thr_row, hT, x2, idx9);
    k_ac    <<<dim3(49, 4, BB), 256, 0, stream>>>(h, gconv_w, gconv_b, acT);
    k_gather<<<dim3(196, BB), 256, 0, stream>>>(acT, idx9, gT);
    k_fc2   <<<dim3(196, BB), 256, 0, stream>>>(gT, fc2_w, fc2_b, out, sa_in);
    k_att   <<<dim3(13, BB), 256, 0, stream>>>(sa_in, sa_w, x, out);
}

// Round 18
// 227.491 us; speedup vs baseline: 1.1606x; 1.0911x over previous
//
#include <hip/hip_runtime.h>

#define BB 4
#define CC 96
#define NN 3136
#define FLTMAX 3.402823466e+38f
#define CAP 44
#define DELTA 1.0f

typedef unsigned short ushort_t;
typedef __attribute__((ext_vector_type(8))) short bf16x8;
typedef __attribute__((ext_vector_type(4))) float f32x4;

// fp32 -> bf16 round-to-nearest-even
__device__ __forceinline__ ushort_t f2bf(float f) {
    unsigned u = __float_as_uint(f);
    unsigned r = (u + 0x7fff + ((u >> 16) & 1)) >> 16;
    return (ushort_t)r;
}
__device__ __forceinline__ float bf2f(ushort_t us) {
    return __uint_as_float(((unsigned)us) << 16);
}

// htile layout (per batch):
//   idx(n,c) = (((n>>5)*12 + (c>>3))*32 + (n&31))*8 + (c&7)

// ---------------- K1: fc1 -> h (b,c,n) + x2 + bf16 htile (hi only) + hT ------
__global__ __launch_bounds__(256) void k_fc1(const float* __restrict__ x, const float* __restrict__ w,
                                             const float* __restrict__ bias, float* __restrict__ h,
                                             float* __restrict__ x2g,
                                             ushort_t* __restrict__ hAhi,
                                             float* __restrict__ hT) {
    __shared__ float sm[96 * 98 + 96 * 64];
    float* wT = sm;              // [c][o] pad 98
    float* xl = sm + 96 * 98;    // [c][64]
    const int tid = threadIdx.x;
    const int n0 = blockIdx.x * 64;
    const int b = blockIdx.y;
    for (int i = tid; i < 96 * 96; i += 256) {
        int o = i / 96, c = i - o * 96;
        wT[c * 98 + o] = w[i];
    }
    const float* xb = x + (size_t)b * CC * NN;
    for (int i = tid; i < 96 * 64; i += 256) {
        int c = i >> 6, nl = i & 63;
        xl[i] = xb[(size_t)c * NN + n0 + nl];
    }
    __syncthreads();
    const int tr = tid >> 4, tc = tid & 15;
    float acc[6][4];
#pragma unroll
    for (int i = 0; i < 6; ++i)
#pragma unroll
        for (int j = 0; j < 4; ++j) acc[i][j] = 0.f;
#pragma unroll 4
    for (int c = 0; c < 96; ++c) {
        float4 xv = *(const float4*)&xl[c * 64 + tc * 4];
        const float* wp = &wT[c * 98 + tr * 6];
        float2 w01 = *(const float2*)(wp);
        float2 w23 = *(const float2*)(wp + 2);
        float2 w45 = *(const float2*)(wp + 4);
        float wv[6] = {w01.x, w01.y, w23.x, w23.y, w45.x, w45.y};
        float xj[4] = {xv.x, xv.y, xv.z, xv.w};
#pragma unroll
        for (int i = 0; i < 6; ++i)
#pragma unroll
            for (int j = 0; j < 4; ++j) acc[i][j] = fmaf(wv[i], xj[j], acc[i][j]);
    }
    float* hb = h + (size_t)b * CC * NN;
    float* hTb = hT + (size_t)b * NN * 96;
    ushort_t* thi = hAhi + (size_t)b * 602112;
#pragma unroll
    for (int i = 0; i < 6; ++i) {
        float bi = bias[tr * 6 + i];
        acc[i][0] += bi; acc[i][1] += bi; acc[i][2] += bi; acc[i][3] += bi;
        float4 o4 = make_float4(acc[i][0], acc[i][1], acc[i][2], acc[i][3]);
        *(float4*)&hb[(size_t)(tr * 6 + i) * NN + n0 + tc * 4] = o4;
        const int c = tr * 6 + i;
        const int cpart = c >> 3;   // 12 parts of 8 channels
#pragma unroll
        for (int j = 0; j < 4; ++j) {
            const int n = n0 + tc * 4 + j;
            const int idx = (((n >> 5) * 12 + cpart) * 32 + (n & 31)) * 8 + (c & 7);
            thi[idx] = f2bf(acc[i][j]);
            hTb[(size_t)n * 96 + c] = acc[i][j];
        }
    }
    __syncthreads();   // wT/xl reads done -> reuse sm[0..1024) for x2 partials
#pragma unroll
    for (int j = 0; j < 4; ++j) {
        float s = 0.f;
#pragma unroll
        for (int i = 0; i < 6; ++i) s = fmaf(acc[i][j], acc[i][j], s);
        sm[tr * 64 + tc * 4 + j] = s;
    }
    __syncthreads();
    if (tid < 64) {
        float s = 0.f;
#pragma unroll
        for (int t = 0; t < 16; ++t) s += sm[t * 64 + tid];
        x2g[(size_t)b * NN + n0 + tid] = s;
    }
}

// hi-only MFMA tile body: 12 loads, 12 MFMA
#define MFMA_TILE_HI(t, acc0, acc1, acc2, acc3)                                       \
    {                                                                                 \
        const int abase_ = (t) * 6144;                                                \
        _Pragma("unroll")                                                             \
        for (int ks_ = 0; ks_ < 3; ++ks_) {                                           \
            const int base_ = abase_ + ks_ * 1024;                                    \
            bf16x8 a0_ = *(const bf16x8*)(hHi + base_ + aoff0);                       \
            bf16x8 a1_ = *(const bf16x8*)(hHi + base_ + aoff1);                       \
            bf16x8 a2_ = *(const bf16x8*)(hHi + base_ + 3072 + aoff0);                \
            bf16x8 a3_ = *(const bf16x8*)(hHi + base_ + 3072 + aoff1);                \
            acc0 = __builtin_amdgcn_mfma_f32_16x16x32_bf16(a0_, bhi[ks_], acc0, 0, 0, 0); \
            acc1 = __builtin_amdgcn_mfma_f32_16x16x32_bf16(a1_, bhi[ks_], acc1, 0, 0, 0); \
            acc2 = __builtin_amdgcn_mfma_f32_16x16x32_bf16(a2_, bhi[ks_], acc2, 0, 0, 0); \
            acc3 = __builtin_amdgcn_mfma_f32_16x16x32_bf16(a3_, bhi[ks_], acc3, 0, 0, 0); \
        }                                                                             \
    }

// ---------------- K3: threshold KNN filter, hi-only + reg score cache --------
// grid (98 n-blocks of 32, 4 m-quarters, B), 256 thr = 4 waves.
__global__ __launch_bounds__(256) void k_dist(const ushort_t* __restrict__ hAhi,
                                              const float* __restrict__ x2,
                                              int* __restrict__ cand_cnt,
                                              int* __restrict__ cand_idx,
                                              float* __restrict__ thr_row) {
    __shared__ float thrb[32][24];
    __shared__ float thr_s[32];
    __shared__ int   cnt[32];
    __shared__ int   list[32][CAP];
    const int tid = threadIdx.x;
    const int nb = blockIdx.x, q = blockIdx.y, b = blockIdx.z;
    const int w = tid >> 6, l = tid & 63;
    const int ln = l & 15, lq = l >> 4;
    const int p = w >> 1;
    const int kl_off = lq * 256;
    const ushort_t* hHi = hAhi + (size_t)b * 602112;
    const float* x2b = x2 + (size_t)b * NN;

    const int lane32n = (w & 1) * 16 + ln;
    bf16x8 bhi[3];
#pragma unroll
    for (int ks = 0; ks < 3; ++ks) {
        const int off = nb * 3072 + ks * 1024 + kl_off + lane32n * 8;
        bhi[ks] = *(const bf16x8*)(hHi + off);
    }
    const int aoff0 = kl_off + ln * 8;
    const int aoff1 = kl_off + (16 + ln) * 8;

    // quarter boundaries over 49 tiles: {0,13,25,37,49}
    const int qb0 = (q == 0) ? 0 : (q == 1) ? 13 : (q == 2) ? 25 : 37;
    const int qb1 = (q == 0) ? 13 : (q == 1) ? 25 : (q == 2) ? 37 : 49;
    const int tstart = qb0 + p;

    unsigned scache[7][8];   // packed bf16 scores: [tile][msub*2 + pair]
    // ---- Phase A ----
    float lv0 = FLTMAX, lv1 = FLTMAX, lv2 = FLTMAX;
#pragma unroll
    for (int ti = 0; ti < 7; ++ti) {
        const int t = tstart + 2 * ti;
        if (t < qb1) {
            const int m0 = t * 64;
            f32x4 acc0 = {0.f, 0.f, 0.f, 0.f}, acc1 = {0.f, 0.f, 0.f, 0.f};
            f32x4 acc2 = {0.f, 0.f, 0.f, 0.f}, acc3 = {0.f, 0.f, 0.f, 0.f};
            MFMA_TILE_HI(t, acc0, acc1, acc2, acc3);
#pragma unroll
            for (int msub = 0; msub < 4; ++msub) {
                f32x4 a = (msub == 0) ? acc0 : (msub == 1) ? acc1 : (msub == 2) ? acc2 : acc3;
                const int mb = m0 + msub * 16 + lq * 4;
                float4 xv = *(const float4*)&x2b[mb];
                float s0 = fmaf(-2.f, a[0], xv.x);
                float s1 = fmaf(-2.f, a[1], xv.y);
                float s2 = fmaf(-2.f, a[2], xv.z);
                float s3 = fmaf(-2.f, a[3], xv.w);
                scache[ti][msub * 2 + 0] = ((unsigned)f2bf(s0) << 16) | (unsigned)f2bf(s1);
                scache[ti][msub * 2 + 1] = ((unsigned)f2bf(s2) << 16) | (unsigned)f2bf(s3);
                float ss[4] = {s0, s1, s2, s3};
#pragma unroll
                for (int r = 0; r < 4; ++r) {
                    float v = ss[r];
                    float t0 = fminf(lv0, v);
                    lv0 = fmaxf(t0, lv1);
                    float t1 = fminf(t0, lv1);
                    lv1 = fmaxf(t1, lv2);
                    lv2 = fminf(t1, lv2);
                }
            }
        }
    }
    {
        const int sidx = (p * 4 + lq) * 3;
        thrb[lane32n][sidx + 0] = lv0;
        thrb[lane32n][sidx + 1] = lv1;
        thrb[lane32n][sidx + 2] = lv2;
    }
    __syncthreads();
    if (tid < 32) {
        float tmp[24];
#pragma unroll
        for (int j = 0; j < 24; ++j) tmp[j] = thrb[tid][j];
        float last = FLTMAX;
        for (int kk = 0; kk < 9; ++kk) {
            float mn = FLTMAX; int ms = 0;
            for (int j = 0; j < 24; ++j)
                if (tmp[j] < mn) { mn = tmp[j]; ms = j; }
            tmp[ms] = FLTMAX;
            last = mn;
        }
        thr_s[tid] = last + DELTA;
        cnt[tid] = 0;
        thr_row[((size_t)b * NN + nb * 32 + tid) * 4 + q] = last + DELTA;
    }
    __syncthreads();
    const float thr = thr_s[lane32n];

    // ---- Phase B: scan cached scores, emit all <= thr (no loads/MFMA) ----
#pragma unroll
    for (int ti = 0; ti < 7; ++ti) {
        const int t = tstart + 2 * ti;
        if (t < qb1) {
            const int m0 = t * 64;
#pragma unroll
            for (int msub = 0; msub < 4; ++msub) {
                const int mb = m0 + msub * 16 + lq * 4;
                const unsigned u01 = scache[ti][msub * 2 + 0];
                const unsigned u23 = scache[ti][msub * 2 + 1];
                unsigned bits[4] = {u01 >> 16, u01 & 0xffffu, u23 >> 16, u23 & 0xffffu};
#pragma unroll
                for (int r = 0; r < 4; ++r) {
                    if (bf2f((ushort_t)bits[r]) <= thr) {
                        int pos = atomicAdd(&cnt[lane32n], 1);
                        if (pos < CAP) list[lane32n][pos] = (int)((bits[r] << 16) | (unsigned)(mb + r));
                    }
                }
            }
        }
    }
    __syncthreads();
    // writeout
    const size_t rowbase = (size_t)b * NN + nb * 32;
    if (tid < 32) cand_cnt[(rowbase + tid) * 4 + q] = min(cnt[tid], CAP);
    for (int i = tid; i < 32 * CAP; i += 256) {
        int r = i / CAP, j = i - r * CAP;
        if (j < min(cnt[r], CAP))
            cand_idx[((rowbase + r) * 4 + q) * CAP + j] = list[r][j];
    }
}

// ---------------- K4: compact + cooperative 4-lane dots + count-rank ---------
// grid 3136 blocks x 256 thr = 4 waves; one wave per row n.
// cutoff = min_q thr_row[n][q] (valid bound, DELTA >= 2*approx-error).
// 1) compact passing cjs into LDS (set-deterministic).
// 2) cooperative dots: candidate per 4-lane group; lane loads its 96B quarter
//    (16 rows/instr instead of 64 -> 4x fewer transactions per instruction),
//    2x shfl_xor completes the dot.
// 3) rank-by-counting over compacted (v,cj) list -> ordered idx9.
__global__ __launch_bounds__(256) void k_merge9(const int* __restrict__ cand_cnt,
                                                const int* __restrict__ cand_idx,
                                                const float* __restrict__ thr_row,
                                                const float* __restrict__ hT,
                                                const float* __restrict__ x2,
                                                int* __restrict__ idx9) {
    __shared__ int  np[4];
    __shared__ int  cl[4][192];
    __shared__ int2 vl[4][192];
    const int tid = threadIdx.x;
    const int wv = tid >> 6, lane = tid & 63;
    const size_t n = (size_t)blockIdx.x * 4 + wv;
    const int b = (int)(n / NN);
    const int nn = (int)(n - (size_t)b * NN);
    const int c0 = cand_cnt[n * 4 + 0];
    const int c1 = cand_cnt[n * 4 + 1];
    const int c2 = cand_cnt[n * 4 + 2];
    const int c3 = cand_cnt[n * 4 + 3];
    const int p1 = c0, p2 = c0 + c1, p3 = c0 + c1 + c2;
    const int ct = p3 + c3;
    const float cutoff = fminf(fminf(thr_row[n * 4 + 0], thr_row[n * 4 + 1]),
                               fminf(thr_row[n * 4 + 2], thr_row[n * 4 + 3]));
    if (lane == 0) np[wv] = 0;
    __syncthreads();
    // 1) compact passing candidates (uniform 3-trip loop, predicated)
#pragma unroll
    for (int t = 0; t < 3; ++t) {
        const int j = lane + 64 * t;
        if (j < ct) {
            const int qq = (j >= p1) + (j >= p2) + (j >= p3);
            const int base = (qq == 0) ? 0 : (qq == 1) ? p1 : (qq == 2) ? p2 : p3;
            const unsigned u = (unsigned)cand_idx[(n * 4 + qq) * CAP + (j - base)];
            const float av = bf2f((ushort_t)(u >> 16));
            if (av <= cutoff) {
                const int pos = atomicAdd(&np[wv], 1);
                cl[wv][pos] = (int)(u & 0xffffu);
            }
        }
    }
    __syncthreads();
    const int npw = np[wv];
    const int npmax = max(max(np[0], np[1]), max(np[2], np[3]));
    const float* hTb = hT + (size_t)b * NN * 96;
    const float* x2b = x2 + (size_t)b * NN;
    // 2) cooperative dots: lane = (slot, part); preload own-row quarter
    const int part = lane & 3, slot = lane >> 2;
    float4 ro[6];
    {
        const float* own = hTb + (size_t)nn * 96 + part * 24;
#pragma unroll
        for (int i = 0; i < 6; ++i) ro[i] = *(const float4*)&own[i * 4];
    }
    for (int base = 0; base < npmax; base += 16) {
        const int s = base + slot;
        const bool act = (s < npw);
        int cj = 0;
        float dot = 0.f;
        if (act) {
            cj = cl[wv][s];
            const float* cr = hTb + (size_t)cj * 96 + part * 24;
#pragma unroll
            for (int i = 0; i < 6; ++i) {
                float4 cv = *(const float4*)&cr[i * 4];
                dot = fmaf(ro[i].x, cv.x, dot);
                dot = fmaf(ro[i].y, cv.y, dot);
                dot = fmaf(ro[i].z, cv.z, dot);
                dot = fmaf(ro[i].w, cv.w, dot);
            }
        }
        dot += __shfl_xor(dot, 1, 64);
        dot += __shfl_xor(dot, 2, 64);
        if (act && part == 0) {
            const float v = fmaf(-2.f, dot, x2b[cj]);
            vl[wv][s] = make_int2(__float_as_int(v), cj);
        }
    }
    __syncthreads();
    // 3) rank-by-counting over compacted list -> ordered idx9
    int2 mine[3]; int rk[3];
#pragma unroll
    for (int t = 0; t < 3; ++t) {
        const int s = lane + 64 * t;
        mine[t] = (s < npw) ? vl[wv][s] : make_int2(0x7f7fffff, 0x7fffffff);
        rk[t] = 0;
    }
    for (int j2 = 0; j2 < npw; ++j2) {
        const int2 e = vl[wv][j2];
        const float ev = __int_as_float(e.x);
#pragma unroll
        for (int t = 0; t < 3; ++t) {
            const float mv = __int_as_float(mine[t].x);
            rk[t] += (ev < mv || (ev == mv && e.y < mine[t].y)) ? 1 : 0;
        }
    }
    int* dst = idx9 + n * 9;
#pragma unroll
    for (int t = 0; t < 3; ++t) {
        const int s = lane + 64 * t;
        if (s < npw && rk[t] < 9) dst[rk[t]] = mine[t].y;
    }
}

// ---------------- K5: [U;V] @ h -> acT bf16 (b,n,384); weights fused ---------
__global__ __launch_bounds__(256) void k_ac(const float* __restrict__ h, const float* __restrict__ gw,
                                            const float* __restrict__ gb, ushort_t* __restrict__ acT) {
    __shared__ float sm[96 * 98 + 96 * 64];
    float* wT = sm;
    float* hl = sm + 96 * 98;
    const int tid = threadIdx.x;
    const int n0 = blockIdx.x * 64, ot = blockIdx.y, b = blockIdx.z;
    // rows 0..191 of M = W1 - W2, rows 192..383 = W2  (W=[W1|W2], 192x192)
    for (int i = tid; i < 96 * 96; i += 256) {
        int o = i / 96, c = i - o * 96;
        float v;
        if (ot < 2) {
            const float* gwp = gw + (size_t)(ot * 96 + o) * 192;
            v = gwp[c] - gwp[96 + c];
        } else {
            v = gw[(size_t)((ot - 2) * 96 + o) * 192 + 96 + c];
        }
        wT[c * 98 + o] = v;
    }
    const float* hb = h + (size_t)b * CC * NN;
    for (int i = tid; i < 96 * 64; i += 256) {
        int c = i >> 6, nl = i & 63;
        hl[i] = hb[(size_t)c * NN + n0 + nl];
    }
    __syncthreads();
    const int tr = tid >> 4, tc = tid & 15;
    float acc[6][4];
#pragma unroll
    for (int i = 0; i < 6; ++i)
#pragma unroll
        for (int j = 0; j < 4; ++j) acc[i][j] = 0.f;
#pragma unroll 4
    for (int c = 0; c < 96; ++c) {
        float4 xv = *(const float4*)&hl[c * 64 + tc * 4];
        const float* wp = &wT[c * 98 + tr * 6];
        float2 w01 = *(const float2*)(wp);
        float2 w23 = *(const float2*)(wp + 2);
        float2 w45 = *(const float2*)(wp + 4);
        float wv[6] = {w01.x, w01.y, w23.x, w23.y, w45.x, w45.y};
        float xj[4] = {xv.x, xv.y, xv.z, xv.w};
#pragma unroll
        for (int i = 0; i < 6; ++i)
#pragma unroll
            for (int j = 0; j < 4; ++j) acc[i][j] = fmaf(wv[i], xj[j], acc[i][j]);
    }
    const int obase = ot * 96 + tr * 6;
    float bs[6];
#pragma unroll
    for (int i = 0; i < 6; ++i) bs[i] = (ot < 2) ? gb[obase + i] : 0.f;
#pragma unroll
    for (int j = 0; j < 4; ++j) {
        ushort_t* dst = acT + ((size_t)b * NN + n0 + tc * 4 + j) * 384 + obase;
        ushort2 p0, p1, p2;
        p0.x = f2bf(acc[0][j] + bs[0]); p0.y = f2bf(acc[1][j] + bs[1]);
        p1.x = f2bf(acc[2][j] + bs[2]); p1.y = f2bf(acc[3][j] + bs[3]);
        p2.x = f2bf(acc[4][j] + bs[4]); p2.y = f2bf(acc[5][j] + bs[5]);
        *(ushort2*)(dst + 0) = p0;
        *(ushort2*)(dst + 2) = p1;
        *(ushort2*)(dst + 4) = p2;
    }
}

// ---------------- K6: gather neighbors (bf16), k-max, relu -> gT fp32 --------
__global__ __launch_bounds__(256) void k_gather(const ushort_t* __restrict__ acT,
                                                const int* __restrict__ idx9,
                                                float* __restrict__ gT) {
    const int lane = threadIdx.x & 63;
    const int wv = threadIdx.x >> 6;
    const int b = blockIdx.y;
    const int nb = blockIdx.x * 16 + wv * 4;
    for (int r = 0; r < 4; ++r) {
        const int n = nb + r;
        const ushort_t* ar = acT + ((size_t)b * NN + n) * 384;
        float a0 = bf2f(ar[lane]), a1 = bf2f(ar[lane + 64]), a2 = bf2f(ar[lane + 128]);
        const int* ip = idx9 + ((size_t)b * NN + n) * 9;
        int jj[9];
#pragma unroll
        for (int k = 0; k < 9; ++k) jj[k] = ip[k];
        float m0 = -FLTMAX, m1 = -FLTMAX, m2 = -FLTMAX;
#pragma unroll
        for (int k = 0; k < 9; ++k) {
            const ushort_t* cr = acT + ((size_t)b * NN + jj[k]) * 384 + 192;
            m0 = fmaxf(m0, a0 + bf2f(cr[lane]));
            m1 = fmaxf(m1, a1 + bf2f(cr[lane + 64]));
            m2 = fmaxf(m2, a2 + bf2f(cr[lane + 128]));
        }
        float* gr = gT + ((size_t)b * NN + n) * 192;
        gr[lane] = fmaxf(m0, 0.f);
        gr[lane + 64] = fmaxf(m1, 0.f);
        gr[lane + 128] = fmaxf(m2, 0.f);
    }
}

// ---------------- K7: fc2 (NT gemm, 16-col tiles) -> out + mean/max ----------
// grid (196, BB): 16 cols/block, 96 out-ch; thread (tr,tc) owns 6 ch x 1 col.
__global__ __launch_bounds__(256) void k_fc2(const float* __restrict__ gT, const float* __restrict__ w,
                                             const float* __restrict__ bias, float* __restrict__ out,
                                             float* __restrict__ sa_in) {
    __shared__ float Wc[96 * 36];
    __shared__ float Gc[16 * 36];
    __shared__ float red[2][16][17];
    const int tid = threadIdx.x;
    const int n0 = blockIdx.x * 16, b = blockIdx.y;
    const int tr = tid >> 4, tc = tid & 15;
    float acc[6];
#pragma unroll
    for (int i = 0; i < 6; ++i) acc[i] = 0.f;
    for (int kc = 0; kc < 192; kc += 32) {
        for (int i = tid; i < 96 * 32; i += 256) {
            int c = i >> 5, k = i & 31;
            Wc[c * 36 + k] = w[(size_t)c * 192 + kc + k];
        }
        for (int i = tid; i < 16 * 32; i += 256) {
            int nl = i >> 5, k = i & 31;
            Gc[nl * 36 + k] = gT[((size_t)b * NN + n0 + nl) * 192 + kc + k];
        }
        __syncthreads();
#pragma unroll
        for (int k = 0; k < 32; k += 4) {
            float4 gv = *(const float4*)&Gc[tc * 36 + k];
#pragma unroll
            for (int i = 0; i < 6; ++i) {
                float4 wv = *(const float4*)&Wc[(tr * 6 + i) * 36 + k];
                acc[i] = fmaf(wv.x, gv.x, acc[i]);
                acc[i] = fmaf(wv.y, gv.y, acc[i]);
                acc[i] = fmaf(wv.z, gv.z, acc[i]);
                acc[i] = fmaf(wv.w, gv.w, acc[i]);
            }
        }
        __syncthreads();
    }
    float* ob = out + (size_t)b * CC * NN;
    float ps = 0.f, pm = -FLTMAX;
#pragma unroll
    for (int i = 0; i < 6; ++i) {
        float o = acc[i] + bias[tr * 6 + i];
        ob[(size_t)(tr * 6 + i) * NN + n0 + tc] = o;
        ps += o;
        pm = fmaxf(pm, o);
    }
    red[0][tr][tc] = ps;
    red[1][tr][tc] = pm;
    __syncthreads();
    if (tid < 16) {
        float s_ = 0.f, m_ = -FLTMAX;
#pragma unroll
        for (int t = 0; t < 16; ++t) { s_ += red[0][t][tid]; m_ = fmaxf(m_, red[1][t][tid]); }
        sa_in[(size_t)b * 2 * NN + n0 + tid] = s_ * (1.0f / 96.0f);
        sa_in[(size_t)b * 2 * NN + NN + n0 + tid] = m_;
    }
}

// ---------------- K9: 7x7 conv + sigmoid + out*att + shortcut (in place) -----
__global__ __launch_bounds__(256) void k_att(const float* __restrict__ sa_in, const float* __restrict__ sw,
                                             const float* __restrict__ x, float* __restrict__ out) {
    int n = blockIdx.x * 256 + threadIdx.x;
    int b = blockIdx.y;
    if (n >= NN) return;
    int y = n / 56, xw = n - y * 56;
    float acc = 0.f;
#pragma unroll
    for (int ci = 0; ci < 2; ++ci) {
        const float* sb = sa_in + ((size_t)b * 2 + ci) * NN;
#pragma unroll
        for (int dy = 0; dy < 7; ++dy) {
            int yy = y + dy - 3;
            if ((unsigned)yy < 56u) {
#pragma unroll
                for (int dx = 0; dx < 7; ++dx) {
                    int xx = xw + dx - 3;
                    if ((unsigned)xx < 56u)
                        acc = fmaf(sb[yy * 56 + xx], sw[(ci * 7 + dy) * 7 + dx], acc);
                }
            }
        }
    }
    float att = 1.f / (1.f + expf(-acc));
    const float* xb = x + (size_t)b * CC * NN + n;
    float* ob = out + (size_t)b * CC * NN + n;
#pragma unroll 4
    for (int c = 0; c < 96; ++c) {
        size_t o = (size_t)c * NN;
        ob[o] = fmaf(ob[o], att, xb[o]);
    }
}

extern "C" void kernel_launch(void* const* d_in, const int* in_sizes, int n_in,
                              void* d_out, int out_size, void* d_ws, size_t ws_size,
                              hipStream_t stream) {
    (void)in_sizes; (void)n_in; (void)out_size; (void)ws_size;
    const float* x       = (const float*)d_in[0];
    const float* fc1_w   = (const float*)d_in[1];
    const float* fc1_b   = (const float*)d_in[2];
    const float* gconv_w = (const float*)d_in[3];
    const float* gconv_b = (const float*)d_in[4];
    const float* fc2_w   = (const float*)d_in[5];
    const float* fc2_b   = (const float*)d_in[6];
    const float* sa_w    = (const float*)d_in[7];
    float* out = (float*)d_out;

    // workspace layout (floats)
    float* ws   = (float*)d_ws;
    float* h    = ws;                                   // 1,204,224
    float* x2   = h + (size_t)BB * CC * NN;             // 12,544
    int*   idx9 = (int*)(x2 + BB * NN);                 // 112,896 ints
    float* regA = (float*)(idx9 + (size_t)BB * NN * 9); // 2,408,448 fl overlay:
    //   k_fc1->k_dist: hAhi (first half) ; k_ac->k_gather: acT bf16 (full)
    ushort_t* hAhi = (ushort_t*)regA;                   // 2,408,448 ushorts
    ushort_t* acT  = (ushort_t*)regA;                   // 4,816,896 ushorts
    float* hT   = regA + 2408448;                       // 1,204,224 fl
    float* regB = hT + 1204224;                         // 2,408,448 fl overlay:
    //   k_dist->k_merge9: cand_idx + cand_cnt + thr_row ; k_gather->k_fc2: gT
    int*   cand_idx = (int*)regB;                       // BB*NN*4*CAP = 2,207,744
    int*   cand_cnt = (int*)(regB + 2207744);           // BB*NN*4 = 50,176
    float* thr_row  = regB + 2207744 + 50176;           // BB*NN*4 = 50,176
    float* gT   = regB;                                 // 2,408,448 fl
    float* sa_in = regB + 2408448;                      // 25,088 fl

    k_fc1   <<<dim3(49, BB), 256, 0, stream>>>(x, fc1_w, fc1_b, h, x2, hAhi, hT);
    k_dist  <<<dim3(98, 4, BB), 256, 0, stream>>>(hAhi, x2, cand_cnt, cand_idx, thr_row);
    k_merge9<<<dim3(3136), 256, 0, stream>>>(cand_cnt, cand_idx, thr_row, hT, x2, idx9);
    k_ac    <<<dim3(49, 4, BB), 256, 0, stream>>>(h, gconv_w, gconv_b, acT);
    k_gather<<<dim3(196, BB), 256, 0, stream>>>(acT, idx9, gT);
    k_fc2   <<<dim3(196, BB), 256, 0, stream>>>(gT, fc2_w, fc2_b, out, sa_in);
    k_att   <<<dim3(13, BB), 256, 0, stream>>>(sa_in, sa_w, x, out);
}

// Round 19
// 226.823 us; speedup vs baseline: 1.1640x; 1.0029x over previous
//
#include <hip/hip_runtime.h>

#define BB 4
#define CC 96
#define NN 3136
#define FLTMAX 3.402823466e+38f
#define CAP 44
#define DELTA 1.0f

typedef unsigned short ushort_t;
typedef __attribute__((ext_vector_type(8))) short bf16x8;
typedef __attribute__((ext_vector_type(4))) float f32x4;

// fp32 -> bf16 round-to-nearest-even
__device__ __forceinline__ ushort_t f2bf(float f) {
    unsigned u = __float_as_uint(f);
    unsigned r = (u + 0x7fff + ((u >> 16) & 1)) >> 16;
    return (ushort_t)r;
}
__device__ __forceinline__ float bf2f(ushort_t us) {
    return __uint_as_float(((unsigned)us) << 16);
}

// branchless top-3-smallest insert (desc: l0 >= l1 >= l2), 3 ops via med3
#define TOP3_INS(v, l0, l1, l2)                                   \
    {                                                             \
        float n0_ = __builtin_amdgcn_fmed3f((v), (l0), (l1));     \
        float n1_ = __builtin_amdgcn_fmed3f((v), (l1), (l2));     \
        float n2_ = fminf((v), (l2));                             \
        (l0) = n0_; (l1) = n1_; (l2) = n2_;                       \
    }

// htile layout (per batch):
//   idx(n,c) = (((n>>5)*12 + (c>>3))*32 + (n&31))*8 + (c&7)

// ---------------- K1: fc1 -> h (b,c,n) + x2 + bf16 htile (hi only) + hT ------
__global__ __launch_bounds__(256) void k_fc1(const float* __restrict__ x, const float* __restrict__ w,
                                             const float* __restrict__ bias, float* __restrict__ h,
                                             float* __restrict__ x2g,
                                             ushort_t* __restrict__ hAhi,
                                             float* __restrict__ hT) {
    __shared__ float sm[96 * 98 + 96 * 64];
    float* wT = sm;              // [c][o] pad 98
    float* xl = sm + 96 * 98;    // [c][64]
    const int tid = threadIdx.x;
    const int n0 = blockIdx.x * 64;
    const int b = blockIdx.y;
    for (int i = tid; i < 96 * 96; i += 256) {
        int o = i / 96, c = i - o * 96;
        wT[c * 98 + o] = w[i];
    }
    const float* xb = x + (size_t)b * CC * NN;
    for (int i = tid; i < 96 * 64; i += 256) {
        int c = i >> 6, nl = i & 63;
        xl[i] = xb[(size_t)c * NN + n0 + nl];
    }
    __syncthreads();
    const int tr = tid >> 4, tc = tid & 15;
    float acc[6][4];
#pragma unroll
    for (int i = 0; i < 6; ++i)
#pragma unroll
        for (int j = 0; j < 4; ++j) acc[i][j] = 0.f;
#pragma unroll 4
    for (int c = 0; c < 96; ++c) {
        float4 xv = *(const float4*)&xl[c * 64 + tc * 4];
        const float* wp = &wT[c * 98 + tr * 6];
        float2 w01 = *(const float2*)(wp);
        float2 w23 = *(const float2*)(wp + 2);
        float2 w45 = *(const float2*)(wp + 4);
        float wv[6] = {w01.x, w01.y, w23.x, w23.y, w45.x, w45.y};
        float xj[4] = {xv.x, xv.y, xv.z, xv.w};
#pragma unroll
        for (int i = 0; i < 6; ++i)
#pragma unroll
            for (int j = 0; j < 4; ++j) acc[i][j] = fmaf(wv[i], xj[j], acc[i][j]);
    }
    float* hb = h + (size_t)b * CC * NN;
    float* hTb = hT + (size_t)b * NN * 96;
    ushort_t* thi = hAhi + (size_t)b * 602112;
#pragma unroll
    for (int i = 0; i < 6; ++i) {
        float bi = bias[tr * 6 + i];
        acc[i][0] += bi; acc[i][1] += bi; acc[i][2] += bi; acc[i][3] += bi;
        float4 o4 = make_float4(acc[i][0], acc[i][1], acc[i][2], acc[i][3]);
        *(float4*)&hb[(size_t)(tr * 6 + i) * NN + n0 + tc * 4] = o4;
        const int c = tr * 6 + i;
        const int cpart = c >> 3;   // 12 parts of 8 channels
#pragma unroll
        for (int j = 0; j < 4; ++j) {
            const int n = n0 + tc * 4 + j;
            const int idx = (((n >> 5) * 12 + cpart) * 32 + (n & 31)) * 8 + (c & 7);
            thi[idx] = f2bf(acc[i][j]);
            hTb[(size_t)n * 96 + c] = acc[i][j];
        }
    }
    __syncthreads();   // wT/xl reads done -> reuse sm[0..1024) for x2 partials
#pragma unroll
    for (int j = 0; j < 4; ++j) {
        float s = 0.f;
#pragma unroll
        for (int i = 0; i < 6; ++i) s = fmaf(acc[i][j], acc[i][j], s);
        sm[tr * 64 + tc * 4 + j] = s;
    }
    __syncthreads();
    if (tid < 64) {
        float s = 0.f;
#pragma unroll
        for (int t = 0; t < 16; ++t) s += sm[t * 64 + tid];
        x2g[(size_t)b * NN + n0 + tid] = s;
    }
}

// hi-only MFMA tile body: 12 loads, 12 MFMA
#define MFMA_TILE_HI(t, acc0, acc1, acc2, acc3)                                       \
    {                                                                                 \
        const int abase_ = (t) * 6144;                                                \
        _Pragma("unroll")                                                             \
        for (int ks_ = 0; ks_ < 3; ++ks_) {                                           \
            const int base_ = abase_ + ks_ * 1024;                                    \
            bf16x8 a0_ = *(const bf16x8*)(hHi + base_ + aoff0);                       \
            bf16x8 a1_ = *(const bf16x8*)(hHi + base_ + aoff1);                       \
            bf16x8 a2_ = *(const bf16x8*)(hHi + base_ + 3072 + aoff0);                \
            bf16x8 a3_ = *(const bf16x8*)(hHi + base_ + 3072 + aoff1);                \
            acc0 = __builtin_amdgcn_mfma_f32_16x16x32_bf16(a0_, bhi[ks_], acc0, 0, 0, 0); \
            acc1 = __builtin_amdgcn_mfma_f32_16x16x32_bf16(a1_, bhi[ks_], acc1, 0, 0, 0); \
            acc2 = __builtin_amdgcn_mfma_f32_16x16x32_bf16(a2_, bhi[ks_], acc2, 0, 0, 0); \
            acc3 = __builtin_amdgcn_mfma_f32_16x16x32_bf16(a3_, bhi[ks_], acc3, 0, 0, 0); \
        }                                                                             \
    }

// ---------------- K3: threshold KNN filter, hi-only + reg score cache --------
// grid (98 n-blocks of 32, 4 m-quarters, B), 256 thr = 4 waves.
// Phase A: hi.hi approx scores via MFMA; dual independent med3 top-3 chains per
//          lane (merged at end -> exact top-3 of lane stream, same staged set
//          as before); scores cached in regs as TRUNCATED bf16 (trunc only
//          lowers values -> emit guarantee preserved).
// thr[row][q] = exact 9th-smallest of staged 24 fp32 values + DELTA.
// Phase B: unpack cached scores, emit (bf16score<<16|m) for all <= thr.
__global__ __launch_bounds__(256) void k_dist(const ushort_t* __restrict__ hAhi,
                                              const float* __restrict__ x2,
                                              int* __restrict__ cand_cnt,
                                              int* __restrict__ cand_idx,
                                              float* __restrict__ thr_row) {
    __shared__ float thrb[32][24];
    __shared__ float thr_s[32];
    __shared__ int   cnt[32];
    __shared__ int   list[32][CAP];
    const int tid = threadIdx.x;
    const int nb = blockIdx.x, q = blockIdx.y, b = blockIdx.z;
    const int w = tid >> 6, l = tid & 63;
    const int ln = l & 15, lq = l >> 4;
    const int p = w >> 1;
    const int kl_off = lq * 256;
    const ushort_t* hHi = hAhi + (size_t)b * 602112;
    const float* x2b = x2 + (size_t)b * NN;

    const int lane32n = (w & 1) * 16 + ln;
    bf16x8 bhi[3];
#pragma unroll
    for (int ks = 0; ks < 3; ++ks) {
        const int off = nb * 3072 + ks * 1024 + kl_off + lane32n * 8;
        bhi[ks] = *(const bf16x8*)(hHi + off);
    }
    const int aoff0 = kl_off + ln * 8;
    const int aoff1 = kl_off + (16 + ln) * 8;

    // quarter boundaries over 49 tiles: {0,13,25,37,49}
    const int qb0 = (q == 0) ? 0 : (q == 1) ? 13 : (q == 2) ? 25 : 37;
    const int qb1 = (q == 0) ? 13 : (q == 1) ? 25 : (q == 2) ? 37 : 49;
    const int tstart = qb0 + p;

    unsigned scache[7][8];   // packed trunc-bf16 scores: [tile][msub*2 + pair]
    // ---- Phase A: dual independent top-3 chains ----
    float A0 = FLTMAX, A1 = FLTMAX, A2 = FLTMAX;
    float B0 = FLTMAX, B1 = FLTMAX, B2 = FLTMAX;
#pragma unroll
    for (int ti = 0; ti < 7; ++ti) {
        const int t = tstart + 2 * ti;
        if (t < qb1) {
            const int m0 = t * 64;
            f32x4 acc0 = {0.f, 0.f, 0.f, 0.f}, acc1 = {0.f, 0.f, 0.f, 0.f};
            f32x4 acc2 = {0.f, 0.f, 0.f, 0.f}, acc3 = {0.f, 0.f, 0.f, 0.f};
            MFMA_TILE_HI(t, acc0, acc1, acc2, acc3);
#pragma unroll
            for (int msub = 0; msub < 4; ++msub) {
                f32x4 a = (msub == 0) ? acc0 : (msub == 1) ? acc1 : (msub == 2) ? acc2 : acc3;
                const int mb = m0 + msub * 16 + lq * 4;
                float4 xv = *(const float4*)&x2b[mb];
                float s0 = fmaf(-2.f, a[0], xv.x);
                float s1 = fmaf(-2.f, a[1], xv.y);
                float s2 = fmaf(-2.f, a[2], xv.z);
                float s3 = fmaf(-2.f, a[3], xv.w);
                scache[ti][msub * 2 + 0] = (__float_as_uint(s0) & 0xffff0000u) |
                                           (__float_as_uint(s1) >> 16);
                scache[ti][msub * 2 + 1] = (__float_as_uint(s2) & 0xffff0000u) |
                                           (__float_as_uint(s3) >> 16);
                TOP3_INS(s0, A0, A1, A2);
                TOP3_INS(s2, B0, B1, B2);
                TOP3_INS(s1, A0, A1, A2);
                TOP3_INS(s3, B0, B1, B2);
            }
        }
    }
    // merge chain B into chain A -> exact top-3 of the lane's full stream
    TOP3_INS(B2, A0, A1, A2);
    TOP3_INS(B1, A0, A1, A2);
    TOP3_INS(B0, A0, A1, A2);
    {
        const int sidx = (p * 4 + lq) * 3;
        thrb[lane32n][sidx + 0] = A0;
        thrb[lane32n][sidx + 1] = A1;
        thrb[lane32n][sidx + 2] = A2;
    }
    __syncthreads();
    if (tid < 32) {
        float tmp[24];
#pragma unroll
        for (int j = 0; j < 24; ++j) tmp[j] = thrb[tid][j];
        float last = FLTMAX;
        for (int kk = 0; kk < 9; ++kk) {
            float mn = FLTMAX; int ms = 0;
            for (int j = 0; j < 24; ++j)
                if (tmp[j] < mn) { mn = tmp[j]; ms = j; }
            tmp[ms] = FLTMAX;
            last = mn;
        }
        thr_s[tid] = last + DELTA;
        cnt[tid] = 0;
        thr_row[((size_t)b * NN + nb * 32 + tid) * 4 + q] = last + DELTA;
    }
    __syncthreads();
    const float thr = thr_s[lane32n];

    // ---- Phase B: scan cached scores, emit all <= thr (no loads/MFMA) ----
#pragma unroll
    for (int ti = 0; ti < 7; ++ti) {
        const int t = tstart + 2 * ti;
        if (t < qb1) {
            const int m0 = t * 64;
#pragma unroll
            for (int msub = 0; msub < 4; ++msub) {
                const int mb = m0 + msub * 16 + lq * 4;
                const unsigned u01 = scache[ti][msub * 2 + 0];
                const unsigned u23 = scache[ti][msub * 2 + 1];
                const float v0 = __uint_as_float(u01 & 0xffff0000u);
                const float v1 = __uint_as_float(u01 << 16);
                const float v2 = __uint_as_float(u23 & 0xffff0000u);
                const float v3 = __uint_as_float(u23 << 16);
                if (v0 <= thr) {
                    int pos = atomicAdd(&cnt[lane32n], 1);
                    if (pos < CAP) list[lane32n][pos] = (int)((u01 & 0xffff0000u) | (unsigned)(mb + 0));
                }
                if (v1 <= thr) {
                    int pos = atomicAdd(&cnt[lane32n], 1);
                    if (pos < CAP) list[lane32n][pos] = (int)((u01 << 16) | (unsigned)(mb + 1));
                }
                if (v2 <= thr) {
                    int pos = atomicAdd(&cnt[lane32n], 1);
                    if (pos < CAP) list[lane32n][pos] = (int)((u23 & 0xffff0000u) | (unsigned)(mb + 2));
                }
                if (v3 <= thr) {
                    int pos = atomicAdd(&cnt[lane32n], 1);
                    if (pos < CAP) list[lane32n][pos] = (int)((u23 << 16) | (unsigned)(mb + 3));
                }
            }
        }
    }
    __syncthreads();
    // writeout
    const size_t rowbase = (size_t)b * NN + nb * 32;
    if (tid < 32) cand_cnt[(rowbase + tid) * 4 + q] = min(cnt[tid], CAP);
    for (int i = tid; i < 32 * CAP; i += 256) {
        int r = i / CAP, j = i - r * CAP;
        if (j < min(cnt[r], CAP))
            cand_idx[((rowbase + r) * 4 + q) * CAP + j] = list[r][j];
    }
}

// ---------------- K4: compact + cooperative 4-lane dots + count-rank ---------
// grid 3136 blocks x 256 thr = 4 waves; one wave per row n.
__global__ __launch_bounds__(256) void k_merge9(const int* __restrict__ cand_cnt,
                                                const int* __restrict__ cand_idx,
                                                const float* __restrict__ thr_row,
                                                const float* __restrict__ hT,
                                                const float* __restrict__ x2,
                                                int* __restrict__ idx9) {
    __shared__ int  np[4];
    __shared__ int  cl[4][192];
    __shared__ int2 vl[4][192];
    const int tid = threadIdx.x;
    const int wv = tid >> 6, lane = tid & 63;
    const size_t n = (size_t)blockIdx.x * 4 + wv;
    const int b = (int)(n / NN);
    const int nn = (int)(n - (size_t)b * NN);
    const int c0 = cand_cnt[n * 4 + 0];
    const int c1 = cand_cnt[n * 4 + 1];
    const int c2 = cand_cnt[n * 4 + 2];
    const int c3 = cand_cnt[n * 4 + 3];
    const int p1 = c0, p2 = c0 + c1, p3 = c0 + c1 + c2;
    const int ct = p3 + c3;
    const float cutoff = fminf(fminf(thr_row[n * 4 + 0], thr_row[n * 4 + 1]),
                               fminf(thr_row[n * 4 + 2], thr_row[n * 4 + 3]));
    if (lane == 0) np[wv] = 0;
    __syncthreads();
    // 1) compact passing candidates (uniform 3-trip loop, predicated)
#pragma unroll
    for (int t = 0; t < 3; ++t) {
        const int j = lane + 64 * t;
        if (j < ct) {
            const int qq = (j >= p1) + (j >= p2) + (j >= p3);
            const int base = (qq == 0) ? 0 : (qq == 1) ? p1 : (qq == 2) ? p2 : p3;
            const unsigned u = (unsigned)cand_idx[(n * 4 + qq) * CAP + (j - base)];
            const float av = bf2f((ushort_t)(u >> 16));
            if (av <= cutoff) {
                const int pos = atomicAdd(&np[wv], 1);
                cl[wv][pos] = (int)(u & 0xffffu);
            }
        }
    }
    __syncthreads();
    const int npw = np[wv];
    const int npmax = max(max(np[0], np[1]), max(np[2], np[3]));
    const float* hTb = hT + (size_t)b * NN * 96;
    const float* x2b = x2 + (size_t)b * NN;
    // 2) cooperative dots: lane = (slot, part); preload own-row quarter
    const int part = lane & 3, slot = lane >> 2;
    float4 ro[6];
    {
        const float* own = hTb + (size_t)nn * 96 + part * 24;
#pragma unroll
        for (int i = 0; i < 6; ++i) ro[i] = *(const float4*)&own[i * 4];
    }
    for (int base = 0; base < npmax; base += 16) {
        const int s = base + slot;
        const bool act = (s < npw);
        int cj = 0;
        float dot = 0.f;
        if (act) {
            cj = cl[wv][s];
            const float* cr = hTb + (size_t)cj * 96 + part * 24;
#pragma unroll
            for (int i = 0; i < 6; ++i) {
                float4 cv = *(const float4*)&cr[i * 4];
                dot = fmaf(ro[i].x, cv.x, dot);
                dot = fmaf(ro[i].y, cv.y, dot);
                dot = fmaf(ro[i].z, cv.z, dot);
                dot = fmaf(ro[i].w, cv.w, dot);
            }
        }
        dot += __shfl_xor(dot, 1, 64);
        dot += __shfl_xor(dot, 2, 64);
        if (act && part == 0) {
            const float v = fmaf(-2.f, dot, x2b[cj]);
            vl[wv][s] = make_int2(__float_as_int(v), cj);
        }
    }
    __syncthreads();
    // 3) rank-by-counting over compacted list -> ordered idx9
    int2 mine[3]; int rk[3];
#pragma unroll
    for (int t = 0; t < 3; ++t) {
        const int s = lane + 64 * t;
        mine[t] = (s < npw) ? vl[wv][s] : make_int2(0x7f7fffff, 0x7fffffff);
        rk[t] = 0;
    }
    for (int j2 = 0; j2 < npw; ++j2) {
        const int2 e = vl[wv][j2];
        const float ev = __int_as_float(e.x);
#pragma unroll
        for (int t = 0; t < 3; ++t) {
            const float mv = __int_as_float(mine[t].x);
            rk[t] += (ev < mv || (ev == mv && e.y < mine[t].y)) ? 1 : 0;
        }
    }
    int* dst = idx9 + n * 9;
#pragma unroll
    for (int t = 0; t < 3; ++t) {
        const int s = lane + 64 * t;
        if (s < npw && rk[t] < 9) dst[rk[t]] = mine[t].y;
    }
}

// ---------------- K5: [U;V] @ h -> acT bf16 (b,n,384); weights fused ---------
__global__ __launch_bounds__(256) void k_ac(const float* __restrict__ h, const float* __restrict__ gw,
                                            const float* __restrict__ gb, ushort_t* __restrict__ acT) {
    __shared__ float sm[96 * 98 + 96 * 64];
    float* wT = sm;
    float* hl = sm + 96 * 98;
    const int tid = threadIdx.x;
    const int n0 = blockIdx.x * 64, ot = blockIdx.y, b = blockIdx.z;
    // rows 0..191 of M = W1 - W2, rows 192..383 = W2  (W=[W1|W2], 192x192)
    for (int i = tid; i < 96 * 96; i += 256) {
        int o = i / 96, c = i - o * 96;
        float v;
        if (ot < 2) {
            const float* gwp = gw + (size_t)(ot * 96 + o) * 192;
            v = gwp[c] - gwp[96 + c];
        } else {
            v = gw[(size_t)((ot - 2) * 96 + o) * 192 + 96 + c];
        }
        wT[c * 98 + o] = v;
    }
    const float* hb = h + (size_t)b * CC * NN;
    for (int i = tid; i < 96 * 64; i += 256) {
        int c = i >> 6, nl = i & 63;
        hl[i] = hb[(size_t)c * NN + n0 + nl];
    }
    __syncthreads();
    const int tr = tid >> 4, tc = tid & 15;
    float acc[6][4];
#pragma unroll
    for (int i = 0; i < 6; ++i)
#pragma unroll
        for (int j = 0; j < 4; ++j) acc[i][j] = 0.f;
#pragma unroll 4
    for (int c = 0; c < 96; ++c) {
        float4 xv = *(const float4*)&hl[c * 64 + tc * 4];
        const float* wp = &wT[c * 98 + tr * 6];
        float2 w01 = *(const float2*)(wp);
        float2 w23 = *(const float2*)(wp + 2);
        float2 w45 = *(const float2*)(wp + 4);
        float wv[6] = {w01.x, w01.y, w23.x, w23.y, w45.x, w45.y};
        float xj[4] = {xv.x, xv.y, xv.z, xv.w};
#pragma unroll
        for (int i = 0; i < 6; ++i)
#pragma unroll
            for (int j = 0; j < 4; ++j) acc[i][j] = fmaf(wv[i], xj[j], acc[i][j]);
    }
    const int obase = ot * 96 + tr * 6;
    float bs[6];
#pragma unroll
    for (int i = 0; i < 6; ++i) bs[i] = (ot < 2) ? gb[obase + i] : 0.f;
#pragma unroll
    for (int j = 0; j < 4; ++j) {
        ushort_t* dst = acT + ((size_t)b * NN + n0 + tc * 4 + j) * 384 + obase;
        ushort2 p0, p1, p2;
        p0.x = f2bf(acc[0][j] + bs[0]); p0.y = f2bf(acc[1][j] + bs[1]);
        p1.x = f2bf(acc[2][j] + bs[2]); p1.y = f2bf(acc[3][j] + bs[3]);
        p2.x = f2bf(acc[4][j] + bs[4]); p2.y = f2bf(acc[5][j] + bs[5]);
        *(ushort2*)(dst + 0) = p0;
        *(ushort2*)(dst + 2) = p1;
        *(ushort2*)(dst + 4) = p2;
    }
}

// ---------------- K6: gather neighbors (bf16), k-max, relu -> gT fp32 --------
__global__ __launch_bounds__(256) void k_gather(const ushort_t* __restrict__ acT,
                                                const int* __restrict__ idx9,
                                                float* __restrict__ gT) {
    const int lane = threadIdx.x & 63;
    const int wv = threadIdx.x >> 6;
    const int b = blockIdx.y;
    const int nb = blockIdx.x * 16 + wv * 4;
    for (int r = 0; r < 4; ++r) {
        const int n = nb + r;
        const ushort_t* ar = acT + ((size_t)b * NN + n) * 384;
        float a0 = bf2f(ar[lane]), a1 = bf2f(ar[lane + 64]), a2 = bf2f(ar[lane + 128]);
        const int* ip = idx9 + ((size_t)b * NN + n) * 9;
        int jj[9];
#pragma unroll
        for (int k = 0; k < 9; ++k) jj[k] = ip[k];
        float m0 = -FLTMAX, m1 = -FLTMAX, m2 = -FLTMAX;
#pragma unroll
        for (int k = 0; k < 9; ++k) {
            const ushort_t* cr = acT + ((size_t)b * NN + jj[k]) * 384 + 192;
            m0 = fmaxf(m0, a0 + bf2f(cr[lane]));
            m1 = fmaxf(m1, a1 + bf2f(cr[lane + 64]));
            m2 = fmaxf(m2, a2 + bf2f(cr[lane + 128]));
        }
        float* gr = gT + ((size_t)b * NN + n) * 192;
        gr[lane] = fmaxf(m0, 0.f);
        gr[lane + 64] = fmaxf(m1, 0.f);
        gr[lane + 128] = fmaxf(m2, 0.f);
    }
}

// ---------------- K7: fc2 (NT gemm, 16-col tiles) -> out + mean/max ----------
__global__ __launch_bounds__(256) void k_fc2(const float* __restrict__ gT, const float* __restrict__ w,
                                             const float* __restrict__ bias, float* __restrict__ out,
                                             float* __restrict__ sa_in) {
    __shared__ float Wc[96 * 36];
    __shared__ float Gc[16 * 36];
    __shared__ float red[2][16][17];
    const int tid = threadIdx.x;
    const int n0 = blockIdx.x * 16, b = blockIdx.y;
    const int tr = tid >> 4, tc = tid & 15;
    float acc[6];
#pragma unroll
    for (int i = 0; i < 6; ++i) acc[i] = 0.f;
    for (int kc = 0; kc < 192; kc += 32) {
        for (int i = tid; i < 96 * 32; i += 256) {
            int c = i >> 5, k = i & 31;
            Wc[c * 36 + k] = w[(size_t)c * 192 + kc + k];
        }
        for (int i = tid; i < 16 * 32; i += 256) {
            int nl = i >> 5, k = i & 31;
            Gc[nl * 36 + k] = gT[((size_t)b * NN + n0 + nl) * 192 + kc + k];
        }
        __syncthreads();
#pragma unroll
        for (int k = 0; k < 32; k += 4) {
            float4 gv = *(const float4*)&Gc[tc * 36 + k];
#pragma unroll
            for (int i = 0; i < 6; ++i) {
                float4 wv = *(const float4*)&Wc[(tr * 6 + i) * 36 + k];
                acc[i] = fmaf(wv.x, gv.x, acc[i]);
                acc[i] = fmaf(wv.y, gv.y, acc[i]);
                acc[i] = fmaf(wv.z, gv.z, acc[i]);
                acc[i] = fmaf(wv.w, gv.w, acc[i]);
            }
        }
        __syncthreads();
    }
    float* ob = out + (size_t)b * CC * NN;
    float ps = 0.f, pm = -FLTMAX;
#pragma unroll
    for (int i = 0; i < 6; ++i) {
        float o = acc[i] + bias[tr * 6 + i];
        ob[(size_t)(tr * 6 + i) * NN + n0 + tc] = o;
        ps += o;
        pm = fmaxf(pm, o);
    }
    red[0][tr][tc] = ps;
    red[1][tr][tc] = pm;
    __syncthreads();
    if (tid < 16) {
        float s_ = 0.f, m_ = -FLTMAX;
#pragma unroll
        for (int t = 0; t < 16; ++t) { s_ += red[0][t][tid]; m_ = fmaxf(m_, red[1][t][tid]); }
        sa_in[(size_t)b * 2 * NN + n0 + tid] = s_ * (1.0f / 96.0f);
        sa_in[(size_t)b * 2 * NN + NN + n0 + tid] = m_;
    }
}

// ---------------- K9: 7x7 conv + sigmoid + out*att + shortcut (in place) -----
__global__ __launch_bounds__(256) void k_att(const float* __restrict__ sa_in, const float* __restrict__ sw,
                                             const float* __restrict__ x, float* __restrict__ out) {
    int n = blockIdx.x * 256 + threadIdx.x;
    int b = blockIdx.y;
    if (n >= NN) return;
    int y = n / 56, xw = n - y * 56;
    float acc = 0.f;
#pragma unroll
    for (int ci = 0; ci < 2; ++ci) {
        const float* sb = sa_in + ((size_t)b * 2 + ci) * NN;
#pragma unroll
        for (int dy = 0; dy < 7; ++dy) {
            int yy = y + dy - 3;
            if ((unsigned)yy < 56u) {
#pragma unroll
                for (int dx = 0; dx < 7; ++dx) {
                    int xx = xw + dx - 3;
                    if ((unsigned)xx < 56u)
                        acc = fmaf(sb[yy * 56 + xx], sw[(ci * 7 + dy) * 7 + dx], acc);
                }
            }
        }
    }
    float att = 1.f / (1.f + expf(-acc));
    const float* xb = x + (size_t)b * CC * NN + n;
    float* ob = out + (size_t)b * CC * NN + n;
#pragma unroll 4
    for (int c = 0; c < 96; ++c) {
        size_t o = (size_t)c * NN;
        ob[o] = fmaf(ob[o], att, xb[o]);
    }
}

extern "C" void kernel_launch(void* const* d_in, const int* in_sizes, int n_in,
                              void* d_out, int out_size, void* d_ws, size_t ws_size,
                              hipStream_t stream) {
    (void)in_sizes; (void)n_in; (void)out_size; (void)ws_size;
    const float* x       = (const float*)d_in[0];
    const float* fc1_w   = (const float*)d_in[1];
    const float* fc1_b   = (const float*)d_in[2];
    const float* gconv_w = (const float*)d_in[3];
    const float* gconv_b = (const float*)d_in[4];
    const float* fc2_w   = (const float*)d_in[5];
    const float* fc2_b   = (const float*)d_in[6];
    const float* sa_w    = (const float*)d_in[7];
    float* out = (float*)d_out;

    // workspace layout (floats)
    float* ws   = (float*)d_ws;
    float* h    = ws;                                   // 1,204,224
    float* x2   = h + (size_t)BB * CC * NN;             // 12,544
    int*   idx9 = (int*)(x2 + BB * NN);                 // 112,896 ints
    float* regA = (float*)(idx9 + (size_t)BB * NN * 9); // 2,408,448 fl overlay:
    //   k_fc1->k_dist: hAhi (first half) ; k_ac->k_gather: acT bf16 (full)
    ushort_t* hAhi = (ushort_t*)regA;                   // 2,408,448 ushorts
    ushort_t* acT  = (ushort_t*)regA;                   // 4,816,896 ushorts
    float* hT   = regA + 2408448;                       // 1,204,224 fl
    float* regB = hT + 1204224;                         // 2,408,448 fl overlay:
    //   k_dist->k_merge9: cand_idx + cand_cnt + thr_row ; k_gather->k_fc2: gT
    int*   cand_idx = (int*)regB;                       // BB*NN*4*CAP = 2,207,744
    int*   cand_cnt = (int*)(regB + 2207744);           // BB*NN*4 = 50,176
    float* thr_row  = regB + 2207744 + 50176;           // BB*NN*4 = 50,176
    float* gT   = regB;                                 // 2,408,448 fl
    float* sa_in = regB + 2408448;                      // 25,088 fl

    k_fc1   <<<dim3(49, BB), 256, 0, stream>>>(x, fc1_w, fc1_b, h, x2, hAhi, hT);
    k_dist  <<<dim3(98, 4, BB), 256, 0, stream>>>(hAhi, x2, cand_cnt, cand_idx, thr_row);
    k_merge9<<<dim3(3136), 256, 0, stream>>>(cand_cnt, cand_idx, thr_row, hT, x2, idx9);
    k_ac    <<<dim3(49, 4, BB), 256, 0, stream>>>(h, gconv_w, gconv_b, acT);
    k_gather<<<dim3(196, BB), 256, 0, stream>>>(acT, idx9, gT);
    k_fc2   <<<dim3(196, BB), 256, 0, stream>>>(gT, fc2_w, fc2_b, out, sa_in);
    k_att   <<<dim3(13, BB), 256, 0, stream>>>(sa_in, sa_w, x, out);
}